// Round 11
// baseline (1876.120 us; speedup 1.0000x reference)
//
#include <hip/hip_runtime.h>
#include <hip/hip_bf16.h>

typedef __bf16 bf16_t;
typedef __bf16 bf16x8 __attribute__((ext_vector_type(8)));
typedef __bf16 bf16x4 __attribute__((ext_vector_type(4)));
typedef float  f32x4  __attribute__((ext_vector_type(4)));
typedef unsigned int u32;
typedef unsigned long long u64;

#define HID 512
#define BATCH 256
#define TIN 168
#define TOUT 48
#define FEAT 128
#define NSTEPS (TIN + TOUT)   // 216
#define NGRP 8                // batch groups
#define NJT 32                // blocks per group (j-tiles of 16)
#define GRPB 32               // batch rows per group

__device__ __forceinline__ float sigmoidf_(float x) {
    x = fminf(fmaxf(x, -30.f), 30.f);
    return 1.f / (1.f + __expf(-x));
}
__device__ __forceinline__ float tanhf_(float x) {
    x = fminf(fmaxf(x, -15.f), 15.f);
    float e = __expf(2.f * x);
    return (e - 1.f) / (e + 1.f);
}

// Coherent IC-through primitives (R4/R10-proven): RELAXED system-scope atomics
// compile to global_load/store ... sc0 sc1 — no cache-maintenance ops.
__device__ __forceinline__ bf16x8 ld_h8(const bf16_t* p) {
    union { u64 q[2]; bf16x8 v; } u;
    u.q[0] = __hip_atomic_load((const u64*)p,     __ATOMIC_RELAXED,
                               __HIP_MEMORY_SCOPE_SYSTEM);
    u.q[1] = __hip_atomic_load((const u64*)p + 1, __ATOMIC_RELAXED,
                               __HIP_MEMORY_SCOPE_SYSTEM);
    return u.v;
}
// one 8B store of 4 consecutive bf16 h-values
__device__ __forceinline__ void st_h4(bf16_t* p, float v0, float v1, float v2, float v3) {
    bf16_t b0 = (bf16_t)v0, b1 = (bf16_t)v1, b2 = (bf16_t)v2, b3 = (bf16_t)v3;
    unsigned short s0, s1, s2, s3;
    __builtin_memcpy(&s0, &b0, 2); __builtin_memcpy(&s1, &b1, 2);
    __builtin_memcpy(&s2, &b2, 2); __builtin_memcpy(&s3, &b3, 2);
    u64 w = (u64)s0 | ((u64)s1 << 16) | ((u64)s2 << 32) | ((u64)s3 << 48);
    __hip_atomic_store((u64*)p, w, __ATOMIC_RELAXED, __HIP_MEMORY_SCOPE_SYSTEM);
}

// ---------------------------------------------------------------------------
// Cast x (B,T,F) fp32 -> Xbf (T,B,F) bf16
__global__ __launch_bounds__(256)
void cast_x_kernel(const float* __restrict__ x, bf16_t* __restrict__ Xbf) {
    int q = blockIdx.x * 256 + threadIdx.x;
    if (q >= BATCH * TIN * (FEAT / 4)) return;
    int f4  = q & 31;
    int rem = q >> 5;
    int t = rem % TIN;
    int b = rem / TIN;
    float4 v = *(const float4*)&x[((size_t)b * TIN + t) * FEAT + f4 * 4];
    bf16x4 o = { (bf16_t)v.x, (bf16_t)v.y, (bf16_t)v.z, (bf16_t)v.w };
    *(bf16x4*)&Xbf[((size_t)t * BATCH + b) * FEAT + f4 * 4] = o;
}

// Build Wcat (2048 x 640) bf16 = [Wih | Whh]
__global__ __launch_bounds__(256)
void cast_wcat_kernel(const float* __restrict__ Wih, const float* __restrict__ Whh,
                      bf16_t* __restrict__ Wcat) {
    int q = blockIdx.x * 256 + threadIdx.x;
    int k4 = q % 160;
    int r  = q / 160;
    if (r >= 2048) return;
    int k = k4 * 4;
    float4 v;
    if (k < FEAT) v = *(const float4*)&Wih[(size_t)r * FEAT + k];
    else          v = *(const float4*)&Whh[(size_t)r * HID + (k - FEAT)];
    bf16x4 o = { (bf16_t)v.x, (bf16_t)v.y, (bf16_t)v.z, (bf16_t)v.w };
    *(bf16x4*)&Wcat[(size_t)r * 640 + k] = o;
}

// Cast W_lin (128 x 512) fp32 -> bf16
__global__ __launch_bounds__(256)
void cast_wlin_kernel(const float* __restrict__ W, bf16_t* __restrict__ Wb) {
    int q = blockIdx.x * 256 + threadIdx.x;
    if (q >= FEAT * HID / 4) return;
    float4 v = *(const float4*)&W[q * 4];
    bf16x4 o = { (bf16_t)v.x, (bf16_t)v.y, (bf16_t)v.z, (bf16_t)v.w };
    *(bf16x4*)&Wb[q * 4] = o;
}

// Wcomb (2048 x 512) = dec_Wih (2048x128) @ W_lin (128x512) + dec_Whh, bf16 out
__global__ __launch_bounds__(256)
void build_wcomb_kernel(const float* __restrict__ dWih, const float* __restrict__ dWhh,
                        const float* __restrict__ Wlin, bf16_t* __restrict__ Wcomb) {
    __shared__ float As[64][128];
    __shared__ float Bs[128][64];
    int r0 = blockIdx.x * 64, c0 = blockIdx.y * 64;
    int tid = threadIdx.x;
    for (int i = tid; i < 64 * 32; i += 256) {
        int rr = i >> 5, cc = (i & 31) << 2;
        *(float4*)&As[rr][cc] = *(const float4*)&dWih[(size_t)(r0 + rr) * 128 + cc];
    }
    for (int i = tid; i < 128 * 16; i += 256) {
        int kk = i >> 4, cc = (i & 15) << 2;
        *(float4*)&Bs[kk][cc] = *(const float4*)&Wlin[(size_t)kk * HID + c0 + cc];
    }
    __syncthreads();
    int tx = tid & 15, ty = tid >> 4;
    float acc[4][4] = {};
    for (int k = 0; k < 128; ++k) {
        float a[4], b[4];
        #pragma unroll
        for (int i = 0; i < 4; ++i) a[i] = As[ty * 4 + i][k];
        #pragma unroll
        for (int j = 0; j < 4; ++j) b[j] = Bs[k][tx * 4 + j];
        #pragma unroll
        for (int i = 0; i < 4; ++i)
            #pragma unroll
            for (int j = 0; j < 4; ++j) acc[i][j] += a[i] * b[j];
    }
    for (int i = 0; i < 4; ++i) {
        int r = r0 + ty * 4 + i;
        for (int j = 0; j < 4; ++j) {
            int cc = c0 + tx * 4 + j;
            Wcomb[(size_t)r * HID + cc] = (bf16_t)(acc[i][j] + dWhh[(size_t)r * HID + cc]);
        }
    }
}

// ---------------------------------------------------------------------------
// Persistent seq2seq LSTM — R10 base + dependency-exact per-wave sync.
// 256 blocks x 256 threads. Block -> (group g = bid&7, j-tile jt = bid>>3).
// Group owns 32 batch rows; block owns 16 hidden cols. Waves: bh = wave&1
// (batch half), gp = wave>>1 (K half). Weights pinned in regs; c register-
// resident. Swapped mfma(W, xh): lane holds batch row b0+l15, 4 consecutive
// hidden cols jq0.. -> ONE 8B h store per lane.
// Flags: one per (block, bh) = 64/group; gp0-bh wave sets its own after its
// drain. Wave (bh,gp) polls ONLY its dependency set (same bh; jt range of
// its K-half). ONE barrier per step; Ex parity-split (proof in R11 notes).

// wave-local wait: lanes 0..nf-1 each poll one flag; wave proceeds when all exit
__device__ __forceinline__ void wave_wait(const u32* flags, int g, int bh,
                                          int jt0, int nf, int lane, u32 epoch) {
    if (lane < nf) {
        const u32* fp = &flags[g * 64 + (jt0 + lane) * 2 + bh];
        while (__hip_atomic_load(fp, __ATOMIC_RELAXED,
                                 __HIP_MEMORY_SCOPE_SYSTEM) < epoch)
            __builtin_amdgcn_s_sleep(1);
    }
}

// gp0 epilogue: merge K-halves from Ex[par], cell update, packed h store,
// drain, set own (block,bh) flag.
__device__ __forceinline__ void cell_store(
    f32x4 (&acc)[4], float (&cacc)[4], const f32x4 (*Exp)[2][64],
    u32* flags, int g, int jt, int bh, int lane, int brow, int jq0,
    u32 epoch_next, bf16_t* __restrict__ hnext)
{
    #pragma unroll
    for (int q = 0; q < 4; ++q)
        acc[q] += Exp[q][bh][lane];
    float hv[4];
    #pragma unroll
    for (int r = 0; r < 4; ++r) {
        float cn = sigmoidf_(acc[1][r]) * cacc[r] + sigmoidf_(acc[0][r]) * tanhf_(acc[2][r]);
        cacc[r] = cn;
        hv[r] = sigmoidf_(acc[3][r]) * tanhf_(cn);
    }
    st_h4(hnext + (size_t)brow * HID + jq0, hv[0], hv[1], hv[2], hv[3]);
    asm volatile("s_waitcnt vmcnt(0)" ::: "memory");   // h acked at IC
    if (lane == 0)
        __hip_atomic_store(&flags[g * 64 + jt * 2 + bh], epoch_next,
                           __ATOMIC_RELAXED, __HIP_MEMORY_SCOPE_SYSTEM);
}

__global__ __launch_bounds__(256, 1)
void lstm_persist(const bf16_t* __restrict__ Xbf,
                  const bf16_t* __restrict__ Wenc, const float* __restrict__ enc_b,
                  const bf16_t* __restrict__ Wdec1, const bf16_t* __restrict__ Wcomb,
                  const float* __restrict__ dec_b,
                  bf16_t* __restrict__ hbufA, bf16_t* __restrict__ hbufB,
                  bf16_t* __restrict__ Hdec, u32* __restrict__ flags)
{
    __shared__ f32x4 Ex[2][4][2][64];   // parity x gate x bh x lane, 16 KB
    const int bid = blockIdx.x;
    const int g   = bid & (NGRP - 1);
    const int jt  = bid >> 3;
    const int j0  = jt * 16;
    const int tid = threadIdx.x;
    const int wave = tid >> 6, lane = tid & 63;
    const int l15 = lane & 15, l4 = lane >> 4;
    const int bh = wave & 1, gp = wave >> 1;
    const int b0 = g * GRPB + bh * 16;
    const int arow = b0 + l15;          // batch row this lane owns (B-operand)
    const int jcol = j0 + l15;          // W row for fragment load (A-operand)
    const int jq0  = j0 + l4 * 4;       // first of this lane's 4 hidden cols

    f32x4 biasE4[4], biasD4[4];
    #pragma unroll
    for (int q = 0; q < 4; ++q) {
        biasE4[q] = *(const f32x4*)&enc_b[q * HID + jq0];
        biasD4[q] = *(const f32x4*)&dec_b[q * HID + jq0];
    }
    float cacc[4] = {0.f, 0.f, 0.f, 0.f};

    bf16x8 Breg[40];
    const int kc0 = gp * 320;    // K-half base for K=640 phases
    // encoder/dec0 dependency set: gp0 needs h cols 0..192 (jt 0..11, same bh);
    // gp1 needs h cols 192..512 (jt 12..31, same bh)
    const int encJt0 = gp ? 12 : 0;
    const int encNf  = gp ? 20 : 12;

    // ---- encoder weight fragments (K=640), pinned
    #pragma unroll
    for (int q = 0; q < 4; ++q)
        #pragma unroll
        for (int i = 0; i < 10; ++i)
            Breg[q * 10 + i] = *(const bf16x8*)(
                Wenc + (size_t)(q * HID + jcol) * 640 + kc0 + i * 32 + l4 * 8);
    #pragma unroll
    for (int n = 0; n < 40; ++n) asm volatile("" : "+v"(Breg[n]));

    // ================= encoder: t = 0..167 =================
    for (int t = 0; t < TIN; ++t) {
        const int par = t & 1;
        const bf16_t* hb = (t & 1) ? hbufB : hbufA;
        bf16_t* hn       = (t & 1) ? hbufA : hbufB;
        bf16x8 a[10];
        // x prefetch (h-independent) BEFORE the wait
        const bf16_t* xb = Xbf + ((size_t)t * BATCH + arow) * FEAT + l4 * 8;
        if (gp == 0) {
            #pragma unroll
            for (int i = 0; i < 4; ++i) a[i] = *(const bf16x8*)(xb + i * 32);
        }
        if (t > 0) wave_wait(flags, g, bh, encJt0, encNf, lane, (u32)t);
        const bf16_t* hbp = hb + (size_t)arow * HID + l4 * 8;
        if (gp == 0) {
            #pragma unroll
            for (int i = 4; i < 10; ++i) a[i] = ld_h8(hbp + (i * 32 - FEAT));
        } else {
            #pragma unroll
            for (int i = 0; i < 10; ++i) a[i] = ld_h8(hbp + (320 - FEAT) + i * 32);
        }
        f32x4 acc[4];
        #pragma unroll
        for (int q = 0; q < 4; ++q)
            acc[q] = (gp == 0) ? biasE4[q] : (f32x4){0.f, 0.f, 0.f, 0.f};
        #pragma unroll
        for (int i = 0; i < 10; ++i)
            #pragma unroll
            for (int q = 0; q < 4; ++q)
                acc[q] = __builtin_amdgcn_mfma_f32_16x16x32_bf16(Breg[q * 10 + i], a[i], acc[q], 0, 0, 0);
        if (gp == 1) {
            #pragma unroll
            for (int q = 0; q < 4; ++q)
                Ex[par][q][bh][lane] = acc[q];
        }
        __syncthreads();    // the ONE barrier: Ex[par] published
        if (gp == 0)
            cell_store(acc, cacc, Ex[par], flags, g, jt, bh, lane, arow, jq0,
                       (u32)(t + 1), hn);
    }

    // ---- decoder step 0 weights (Wdec1, K=640)
    #pragma unroll
    for (int q = 0; q < 4; ++q)
        #pragma unroll
        for (int i = 0; i < 10; ++i)
            Breg[q * 10 + i] = *(const bf16x8*)(
                Wdec1 + (size_t)(q * HID + jcol) * 640 + kc0 + i * 32 + l4 * 8);
    #pragma unroll
    for (int n = 0; n < 40; ++n) asm volatile("" : "+v"(Breg[n]));

    // ================= decoder step 0: t = 168 =================
    {
        const int t = TIN;
        const int par = t & 1;
        bf16x8 a[10];
        const bf16_t* xb = Xbf + ((size_t)(TIN - 1) * BATCH + arow) * FEAT + l4 * 8;
        if (gp == 0) {
            #pragma unroll
            for (int i = 0; i < 4; ++i) a[i] = *(const bf16x8*)(xb + i * 32);
        }
        wave_wait(flags, g, bh, encJt0, encNf, lane, (u32)t);
        // h_168 lives in hbufA (written at t=167)
        const bf16_t* hbp = hbufA + (size_t)arow * HID + l4 * 8;
        if (gp == 0) {
            #pragma unroll
            for (int i = 4; i < 10; ++i) a[i] = ld_h8(hbp + (i * 32 - FEAT));
        } else {
            #pragma unroll
            for (int i = 0; i < 10; ++i) a[i] = ld_h8(hbp + (320 - FEAT) + i * 32);
        }
        f32x4 acc[4];
        #pragma unroll
        for (int q = 0; q < 4; ++q)
            acc[q] = (gp == 0) ? biasD4[q] : (f32x4){0.f, 0.f, 0.f, 0.f};
        #pragma unroll
        for (int i = 0; i < 10; ++i)
            #pragma unroll
            for (int q = 0; q < 4; ++q)
                acc[q] = __builtin_amdgcn_mfma_f32_16x16x32_bf16(Breg[q * 10 + i], a[i], acc[q], 0, 0, 0);
        if (gp == 1) {
            #pragma unroll
            for (int q = 0; q < 4; ++q)
                Ex[par][q][bh][lane] = acc[q];
        }
        __syncthreads();
        if (gp == 0)
            cell_store(acc, cacc, Ex[par], flags, g, jt, bh, lane, arow, jq0,
                       (u32)(t + 1), Hdec);
    }

    // ---- folded decoder weights (Wcomb, K=512)
    const int kd0 = gp * 256;
    const int decJt0 = gp ? 16 : 0;   // gp0: h 0..256 (jt 0..15); gp1: jt 16..31
    #pragma unroll
    for (int q = 0; q < 4; ++q)
        #pragma unroll
        for (int i = 0; i < 8; ++i)
            Breg[q * 8 + i] = *(const bf16x8*)(
                Wcomb + (size_t)(q * HID + jcol) * HID + kd0 + i * 32 + l4 * 8);
    #pragma unroll
    for (int n = 0; n < 32; ++n) asm volatile("" : "+v"(Breg[n]));

    // ================= decoder: t = 169..215 =================
    for (int t = TIN + 1; t < NSTEPS; ++t) {
        const int par = t & 1;
        wave_wait(flags, g, bh, decJt0, 16, lane, (u32)t);
        const bf16_t* hprev = Hdec + (size_t)(t - 1 - TIN) * BATCH * HID
                                   + (size_t)arow * HID + l4 * 8;
        bf16x8 a[8];
        #pragma unroll
        for (int i = 0; i < 8; ++i)
            a[i] = ld_h8(hprev + kd0 + i * 32);
        f32x4 acc[4];
        #pragma unroll
        for (int q = 0; q < 4; ++q)
            acc[q] = (gp == 0) ? biasD4[q] : (f32x4){0.f, 0.f, 0.f, 0.f};
        #pragma unroll
        for (int i = 0; i < 8; ++i)
            #pragma unroll
            for (int q = 0; q < 4; ++q)
                acc[q] = __builtin_amdgcn_mfma_f32_16x16x32_bf16(Breg[q * 8 + i], a[i], acc[q], 0, 0, 0);
        if (gp == 1) {
            #pragma unroll
            for (int q = 0; q < 4; ++q)
                Ex[par][q][bh][lane] = acc[q];
        }
        __syncthreads();
        if (gp == 0)
            cell_store(acc, cacc, Ex[par], flags, g, jt, bh, lane, arow, jq0,
                       (u32)(t + 1), Hdec + (size_t)(t - TIN) * BATCH * HID);
    }
}

// ---------------------------------------------------------------------------
// Final projection: out[b,t,f] = sum_j Hdec[t][b][j] * Wlin[f][j]
__global__ __launch_bounds__(128)
void final_proj_kernel(const bf16_t* __restrict__ Hdec, const bf16_t* __restrict__ Wlin,
                       float* __restrict__ out) {
    int tid = threadIdx.x;
    int wv = tid >> 6, lane = tid & 63;
    int l15 = lane & 15, l4 = lane >> 4;
    int row0 = blockIdx.x * 32 + wv * 16;
    const bf16_t* arow = Hdec + (size_t)(row0 + l15) * HID;
    f32x4 acc[8];
    #pragma unroll
    for (int n = 0; n < 8; ++n) acc[n] = (f32x4){0.f, 0.f, 0.f, 0.f};
    #pragma unroll 4
    for (int kc = 0; kc < HID; kc += 32) {
        bf16x8 af = *(const bf16x8*)(arow + kc + l4 * 8);
        #pragma unroll
        for (int n = 0; n < 8; ++n) {
            bf16x8 bfr = *(const bf16x8*)(Wlin + (size_t)(n * 16 + l15) * HID + kc + l4 * 8);
            acc[n] = __builtin_amdgcn_mfma_f32_16x16x32_bf16(af, bfr, acc[n], 0, 0, 0);
        }
    }
    #pragma unroll
    for (int n = 0; n < 8; ++n) {
        int f = n * 16 + l15;
        #pragma unroll
        for (int r = 0; r < 4; ++r) {
            int row = row0 + l4 * 4 + r;
            int t = row >> 8;
            int b = row & 255;
            out[(size_t)b * (TOUT * FEAT) + (size_t)t * FEAT + f] = acc[n][r];
        }
    }
}

// ---------------------------------------------------------------------------
extern "C" void kernel_launch(void* const* d_in, const int* in_sizes, int n_in,
                              void* d_out, int out_size, void* d_ws, size_t ws_size,
                              hipStream_t stream) {
    const float* x       = (const float*)d_in[0];
    const float* enc_Wih = (const float*)d_in[1];
    const float* enc_Whh = (const float*)d_in[2];
    const float* enc_b   = (const float*)d_in[3];
    const float* dec_Wih = (const float*)d_in[4];
    const float* dec_Whh = (const float*)d_in[5];
    const float* dec_b   = (const float*)d_in[6];
    const float* W_lin   = (const float*)d_in[7];
    float* out = (float*)d_out;

    char* p = (char*)d_ws;
    auto alloc = [&](size_t bytes) -> void* {
        void* r = (void*)p;
        p += (bytes + 255) & ~(size_t)255;
        return r;
    };
    bf16_t* Xbf    = (bf16_t*)alloc((size_t)TIN * BATCH * FEAT * 2);   // 11 MB
    bf16_t* Wenc   = (bf16_t*)alloc((size_t)2048 * 640 * 2);           // 2.6 MB
    bf16_t* Wdec1  = (bf16_t*)alloc((size_t)2048 * 640 * 2);           // 2.6 MB
    bf16_t* Wcomb  = (bf16_t*)alloc((size_t)2048 * HID * 2);           // 2.1 MB
    bf16_t* Wlinb  = (bf16_t*)alloc((size_t)FEAT * HID * 2);           // 128 KB
    bf16_t* hbufA  = (bf16_t*)alloc((size_t)BATCH * HID * 2);          // 256 KB
    bf16_t* hbufB  = (bf16_t*)alloc((size_t)BATCH * HID * 2);          // 256 KB
    bf16_t* Hdec   = (bf16_t*)alloc((size_t)TOUT * BATCH * HID * 2);   // 12.6 MB
    u32* flags     = (u32*)alloc((size_t)NGRP * 64 * 4);               // 2 KB

    // per-launch state init (replay-safe)
    (void)hipMemsetAsync(hbufA, 0, (size_t)BATCH * HID * 2, stream);
    (void)hipMemsetAsync(flags, 0, (size_t)NGRP * 64 * 4, stream);

    // precompute
    cast_x_kernel<<<(BATCH * TIN * (FEAT / 4) + 255) / 256, 256, 0, stream>>>(x, Xbf);
    cast_wcat_kernel<<<(2048 * 160 + 255) / 256, 256, 0, stream>>>(enc_Wih, enc_Whh, Wenc);
    cast_wcat_kernel<<<(2048 * 160 + 255) / 256, 256, 0, stream>>>(dec_Wih, dec_Whh, Wdec1);
    cast_wlin_kernel<<<(FEAT * HID / 4 + 255) / 256, 256, 0, stream>>>(W_lin, Wlinb);
    build_wcomb_kernel<<<dim3(2048 / 64, HID / 64), 256, 0, stream>>>(dec_Wih, dec_Whh, W_lin, Wcomb);

    // all 216 recurrent steps in one persistent kernel
    lstm_persist<<<NGRP * NJT, 256, 0, stream>>>(Xbf, Wenc, enc_b, Wdec1, Wcomb, dec_b,
                                                 hbufA, hbufB, Hdec, flags);

    // batched output projection (48 x 256 rows @ W_lin^T)
    final_proj_kernel<<<(TOUT * BATCH) / 32, 128, 0, stream>>>(Hdec, Wlinb, out);
}

// Round 12
// 1861.155 us; speedup vs baseline: 1.0080x; 1.0080x over previous
//
#include <hip/hip_runtime.h>
#include <hip/hip_bf16.h>

typedef __bf16 bf16_t;
typedef __bf16 bf16x8 __attribute__((ext_vector_type(8)));
typedef __bf16 bf16x4 __attribute__((ext_vector_type(4)));
typedef float  f32x4  __attribute__((ext_vector_type(4)));
typedef unsigned int u32;
typedef unsigned long long u64;

#define HID 512
#define BATCH 256
#define TIN 168
#define TOUT 48
#define FEAT 128
#define NSTEPS (TIN + TOUT)   // 216
#define NGRP 8                // batch groups
#define NJT 32                // blocks per group (j-tiles of 16)
#define GRPB 32               // batch rows per group

__device__ __forceinline__ float sigmoidf_(float x) {
    x = fminf(fmaxf(x, -30.f), 30.f);
    return 1.f / (1.f + __expf(-x));
}
__device__ __forceinline__ float tanhf_(float x) {
    x = fminf(fmaxf(x, -15.f), 15.f);
    float e = __expf(2.f * x);
    return (e - 1.f) / (e + 1.f);
}

// Coherent IC-through primitives (R4/R10-proven): RELAXED system-scope atomics
// compile to global_load/store ... sc0 sc1 — no cache-maintenance ops.
__device__ __forceinline__ bf16x8 ld_h8(const bf16_t* p) {
    union { u64 q[2]; bf16x8 v; } u;
    u.q[0] = __hip_atomic_load((const u64*)p,     __ATOMIC_RELAXED,
                               __HIP_MEMORY_SCOPE_SYSTEM);
    u.q[1] = __hip_atomic_load((const u64*)p + 1, __ATOMIC_RELAXED,
                               __HIP_MEMORY_SCOPE_SYSTEM);
    return u.v;
}
// one 8B store of 4 consecutive bf16 h-values
__device__ __forceinline__ void st_h4(bf16_t* p, float v0, float v1, float v2, float v3) {
    bf16_t b0 = (bf16_t)v0, b1 = (bf16_t)v1, b2 = (bf16_t)v2, b3 = (bf16_t)v3;
    unsigned short s0, s1, s2, s3;
    __builtin_memcpy(&s0, &b0, 2); __builtin_memcpy(&s1, &b1, 2);
    __builtin_memcpy(&s2, &b2, 2); __builtin_memcpy(&s3, &b3, 2);
    u64 w = (u64)s0 | ((u64)s1 << 16) | ((u64)s2 << 32) | ((u64)s3 << 48);
    __hip_atomic_store((u64*)p, w, __ATOMIC_RELAXED, __HIP_MEMORY_SCOPE_SYSTEM);
}

// ---------------------------------------------------------------------------
// Cast x (B,T,F) fp32 -> Xbf (T,B,F) bf16
__global__ __launch_bounds__(256)
void cast_x_kernel(const float* __restrict__ x, bf16_t* __restrict__ Xbf) {
    int q = blockIdx.x * 256 + threadIdx.x;
    if (q >= BATCH * TIN * (FEAT / 4)) return;
    int f4  = q & 31;
    int rem = q >> 5;
    int t = rem % TIN;
    int b = rem / TIN;
    float4 v = *(const float4*)&x[((size_t)b * TIN + t) * FEAT + f4 * 4];
    bf16x4 o = { (bf16_t)v.x, (bf16_t)v.y, (bf16_t)v.z, (bf16_t)v.w };
    *(bf16x4*)&Xbf[((size_t)t * BATCH + b) * FEAT + f4 * 4] = o;
}

// Build Wcat (2048 x 640) bf16 = [Wih | Whh]
__global__ __launch_bounds__(256)
void cast_wcat_kernel(const float* __restrict__ Wih, const float* __restrict__ Whh,
                      bf16_t* __restrict__ Wcat) {
    int q = blockIdx.x * 256 + threadIdx.x;
    int k4 = q % 160;
    int r  = q / 160;
    if (r >= 2048) return;
    int k = k4 * 4;
    float4 v;
    if (k < FEAT) v = *(const float4*)&Wih[(size_t)r * FEAT + k];
    else          v = *(const float4*)&Whh[(size_t)r * HID + (k - FEAT)];
    bf16x4 o = { (bf16_t)v.x, (bf16_t)v.y, (bf16_t)v.z, (bf16_t)v.w };
    *(bf16x4*)&Wcat[(size_t)r * 640 + k] = o;
}

// Cast W_lin (128 x 512) fp32 -> bf16
__global__ __launch_bounds__(256)
void cast_wlin_kernel(const float* __restrict__ W, bf16_t* __restrict__ Wb) {
    int q = blockIdx.x * 256 + threadIdx.x;
    if (q >= FEAT * HID / 4) return;
    float4 v = *(const float4*)&W[q * 4];
    bf16x4 o = { (bf16_t)v.x, (bf16_t)v.y, (bf16_t)v.z, (bf16_t)v.w };
    *(bf16x4*)&Wb[q * 4] = o;
}

// Wcomb (2048 x 512) = dec_Wih (2048x128) @ W_lin (128x512) + dec_Whh, bf16 out
__global__ __launch_bounds__(256)
void build_wcomb_kernel(const float* __restrict__ dWih, const float* __restrict__ dWhh,
                        const float* __restrict__ Wlin, bf16_t* __restrict__ Wcomb) {
    __shared__ float As[64][128];
    __shared__ float Bs[128][64];
    int r0 = blockIdx.x * 64, c0 = blockIdx.y * 64;
    int tid = threadIdx.x;
    for (int i = tid; i < 64 * 32; i += 256) {
        int rr = i >> 5, cc = (i & 31) << 2;
        *(float4*)&As[rr][cc] = *(const float4*)&dWih[(size_t)(r0 + rr) * 128 + cc];
    }
    for (int i = tid; i < 128 * 16; i += 256) {
        int kk = i >> 4, cc = (i & 15) << 2;
        *(float4*)&Bs[kk][cc] = *(const float4*)&Wlin[(size_t)kk * HID + c0 + cc];
    }
    __syncthreads();
    int tx = tid & 15, ty = tid >> 4;
    float acc[4][4] = {};
    for (int k = 0; k < 128; ++k) {
        float a[4], b[4];
        #pragma unroll
        for (int i = 0; i < 4; ++i) a[i] = As[ty * 4 + i][k];
        #pragma unroll
        for (int j = 0; j < 4; ++j) b[j] = Bs[k][tx * 4 + j];
        #pragma unroll
        for (int i = 0; i < 4; ++i)
            #pragma unroll
            for (int j = 0; j < 4; ++j) acc[i][j] += a[i] * b[j];
    }
    for (int i = 0; i < 4; ++i) {
        int r = r0 + ty * 4 + i;
        for (int j = 0; j < 4; ++j) {
            int cc = c0 + tx * 4 + j;
            Wcomb[(size_t)r * HID + cc] = (bf16_t)(acc[i][j] + dWhh[(size_t)r * HID + cc]);
        }
    }
}

// ---------------------------------------------------------------------------
// Persistent seq2seq LSTM — R10 base + dependency-exact per-wave sync.
// 256 blocks x 256 threads. Block -> (group g = bid&7, j-tile jt = bid>>3).
// Group owns 32 batch rows; block owns 16 hidden cols. Waves: bh = wave&1
// (batch half), gp = wave>>1 (K half). Weights pinned in regs; c register-
// resident. Swapped mfma(W, xh): lane holds batch row b0+l15, 4 consecutive
// hidden cols jq0.. -> ONE 8B h store per lane.
// Flags: one per (block, bh) = 64/group; gp0-bh wave sets its own after its
// drain. Wave (bh,gp) polls ONLY its dependency set (same bh; jt range of
// its K-half). ONE barrier per step; Ex parity-split (proof in R11 notes).

// wave-local wait: lanes 0..nf-1 each poll one flag; wave proceeds when all exit
__device__ __forceinline__ void wave_wait(const u32* flags, int g, int bh,
                                          int jt0, int nf, int lane, u32 epoch) {
    if (lane < nf) {
        const u32* fp = &flags[g * 64 + (jt0 + lane) * 2 + bh];
        while (__hip_atomic_load(fp, __ATOMIC_RELAXED,
                                 __HIP_MEMORY_SCOPE_SYSTEM) < epoch)
            __builtin_amdgcn_s_sleep(1);
    }
}

// gp0 epilogue: merge K-halves from Ex[par], cell update, packed h store,
// drain, set own (block,bh) flag.
__device__ __forceinline__ void cell_store(
    f32x4 (&acc)[4], float (&cacc)[4], const f32x4 (*Exp)[2][64],
    u32* flags, int g, int jt, int bh, int lane, int brow, int jq0,
    u32 epoch_next, bf16_t* __restrict__ hnext)
{
    #pragma unroll
    for (int q = 0; q < 4; ++q)
        acc[q] += Exp[q][bh][lane];
    float hv[4];
    #pragma unroll
    for (int r = 0; r < 4; ++r) {
        float cn = sigmoidf_(acc[1][r]) * cacc[r] + sigmoidf_(acc[0][r]) * tanhf_(acc[2][r]);
        cacc[r] = cn;
        hv[r] = sigmoidf_(acc[3][r]) * tanhf_(cn);
    }
    st_h4(hnext + (size_t)brow * HID + jq0, hv[0], hv[1], hv[2], hv[3]);
    asm volatile("s_waitcnt vmcnt(0)" ::: "memory");   // h acked at IC
    if (lane == 0)
        __hip_atomic_store(&flags[g * 64 + jt * 2 + bh], epoch_next,
                           __ATOMIC_RELAXED, __HIP_MEMORY_SCOPE_SYSTEM);
}

__global__ __launch_bounds__(256, 1)
void lstm_persist(const bf16_t* __restrict__ Xbf,
                  const bf16_t* __restrict__ Wenc, const float* __restrict__ enc_b,
                  const bf16_t* __restrict__ Wdec1, const bf16_t* __restrict__ Wcomb,
                  const float* __restrict__ dec_b,
                  bf16_t* __restrict__ hbufA, bf16_t* __restrict__ hbufB,
                  bf16_t* __restrict__ Hdec, u32* __restrict__ flags)
{
    __shared__ f32x4 Ex[2][4][2][64];   // parity x gate x bh x lane, 16 KB
    const int bid = blockIdx.x;
    const int g   = bid & (NGRP - 1);
    const int jt  = bid >> 3;
    const int j0  = jt * 16;
    const int tid = threadIdx.x;
    const int wave = tid >> 6, lane = tid & 63;
    const int l15 = lane & 15, l4 = lane >> 4;
    const int bh = wave & 1, gp = wave >> 1;
    const int b0 = g * GRPB + bh * 16;
    const int arow = b0 + l15;          // batch row this lane owns (B-operand)
    const int jcol = j0 + l15;          // W row for fragment load (A-operand)
    const int jq0  = j0 + l4 * 4;       // first of this lane's 4 hidden cols

    f32x4 biasE4[4], biasD4[4];
    #pragma unroll
    for (int q = 0; q < 4; ++q) {
        biasE4[q] = *(const f32x4*)&enc_b[q * HID + jq0];
        biasD4[q] = *(const f32x4*)&dec_b[q * HID + jq0];
    }
    float cacc[4] = {0.f, 0.f, 0.f, 0.f};

    bf16x8 Breg[40];
    const int kc0 = gp * 320;    // K-half base for K=640 phases
    // encoder/dec0 dependency set: gp0 needs h cols 0..192 (jt 0..11, same bh);
    // gp1 needs h cols 192..512 (jt 12..31, same bh)
    const int encJt0 = gp ? 12 : 0;
    const int encNf  = gp ? 20 : 12;

    // ---- encoder weight fragments (K=640), pinned
    #pragma unroll
    for (int q = 0; q < 4; ++q)
        #pragma unroll
        for (int i = 0; i < 10; ++i)
            Breg[q * 10 + i] = *(const bf16x8*)(
                Wenc + (size_t)(q * HID + jcol) * 640 + kc0 + i * 32 + l4 * 8);
    #pragma unroll
    for (int n = 0; n < 40; ++n) asm volatile("" : "+v"(Breg[n]));

    // ================= encoder: t = 0..167 =================
    for (int t = 0; t < TIN; ++t) {
        const int par = t & 1;
        const bf16_t* hb = (t & 1) ? hbufB : hbufA;
        bf16_t* hn       = (t & 1) ? hbufA : hbufB;
        bf16x8 a[10];
        // x prefetch (h-independent) BEFORE the wait
        const bf16_t* xb = Xbf + ((size_t)t * BATCH + arow) * FEAT + l4 * 8;
        if (gp == 0) {
            #pragma unroll
            for (int i = 0; i < 4; ++i) a[i] = *(const bf16x8*)(xb + i * 32);
        }
        if (t > 0) wave_wait(flags, g, bh, encJt0, encNf, lane, (u32)t);
        const bf16_t* hbp = hb + (size_t)arow * HID + l4 * 8;
        if (gp == 0) {
            #pragma unroll
            for (int i = 4; i < 10; ++i) a[i] = ld_h8(hbp + (i * 32 - FEAT));
        } else {
            #pragma unroll
            for (int i = 0; i < 10; ++i) a[i] = ld_h8(hbp + (320 - FEAT) + i * 32);
        }
        f32x4 acc[4];
        #pragma unroll
        for (int q = 0; q < 4; ++q)
            acc[q] = (gp == 0) ? biasE4[q] : (f32x4){0.f, 0.f, 0.f, 0.f};
        #pragma unroll
        for (int i = 0; i < 10; ++i)
            #pragma unroll
            for (int q = 0; q < 4; ++q)
                acc[q] = __builtin_amdgcn_mfma_f32_16x16x32_bf16(Breg[q * 10 + i], a[i], acc[q], 0, 0, 0);
        if (gp == 1) {
            #pragma unroll
            for (int q = 0; q < 4; ++q)
                Ex[par][q][bh][lane] = acc[q];
        }
        __syncthreads();    // the ONE barrier: Ex[par] published
        if (gp == 0)
            cell_store(acc, cacc, Ex[par], flags, g, jt, bh, lane, arow, jq0,
                       (u32)(t + 1), hn);
    }

    // ---- decoder step 0 weights (Wdec1, K=640)
    #pragma unroll
    for (int q = 0; q < 4; ++q)
        #pragma unroll
        for (int i = 0; i < 10; ++i)
            Breg[q * 10 + i] = *(const bf16x8*)(
                Wdec1 + (size_t)(q * HID + jcol) * 640 + kc0 + i * 32 + l4 * 8);
    #pragma unroll
    for (int n = 0; n < 40; ++n) asm volatile("" : "+v"(Breg[n]));

    // ================= decoder step 0: t = 168 =================
    {
        const int t = TIN;
        const int par = t & 1;
        bf16x8 a[10];
        const bf16_t* xb = Xbf + ((size_t)(TIN - 1) * BATCH + arow) * FEAT + l4 * 8;
        if (gp == 0) {
            #pragma unroll
            for (int i = 0; i < 4; ++i) a[i] = *(const bf16x8*)(xb + i * 32);
        }
        wave_wait(flags, g, bh, encJt0, encNf, lane, (u32)t);
        // h_168 lives in hbufA (written at t=167)
        const bf16_t* hbp = hbufA + (size_t)arow * HID + l4 * 8;
        if (gp == 0) {
            #pragma unroll
            for (int i = 4; i < 10; ++i) a[i] = ld_h8(hbp + (i * 32 - FEAT));
        } else {
            #pragma unroll
            for (int i = 0; i < 10; ++i) a[i] = ld_h8(hbp + (320 - FEAT) + i * 32);
        }
        f32x4 acc[4];
        #pragma unroll
        for (int q = 0; q < 4; ++q)
            acc[q] = (gp == 0) ? biasD4[q] : (f32x4){0.f, 0.f, 0.f, 0.f};
        #pragma unroll
        for (int i = 0; i < 10; ++i)
            #pragma unroll
            for (int q = 0; q < 4; ++q)
                acc[q] = __builtin_amdgcn_mfma_f32_16x16x32_bf16(Breg[q * 10 + i], a[i], acc[q], 0, 0, 0);
        if (gp == 1) {
            #pragma unroll
            for (int q = 0; q < 4; ++q)
                Ex[par][q][bh][lane] = acc[q];
        }
        __syncthreads();
        if (gp == 0)
            cell_store(acc, cacc, Ex[par], flags, g, jt, bh, lane, arow, jq0,
                       (u32)(t + 1), Hdec);
    }

    // ---- folded decoder weights (Wcomb, K=512)
    const int kd0 = gp * 256;
    const int decJt0 = gp ? 16 : 0;   // gp0: h 0..256 (jt 0..15); gp1: jt 16..31
    #pragma unroll
    for (int q = 0; q < 4; ++q)
        #pragma unroll
        for (int i = 0; i < 8; ++i)
            Breg[q * 8 + i] = *(const bf16x8*)(
                Wcomb + (size_t)(q * HID + jcol) * HID + kd0 + i * 32 + l4 * 8);
    #pragma unroll
    for (int n = 0; n < 32; ++n) asm volatile("" : "+v"(Breg[n]));

    // ================= decoder: t = 169..215 =================
    for (int t = TIN + 1; t < NSTEPS; ++t) {
        const int par = t & 1;
        wave_wait(flags, g, bh, decJt0, 16, lane, (u32)t);
        const bf16_t* hprev = Hdec + (size_t)(t - 1 - TIN) * BATCH * HID
                                   + (size_t)arow * HID + l4 * 8;
        bf16x8 a[8];
        #pragma unroll
        for (int i = 0; i < 8; ++i)
            a[i] = ld_h8(hprev + kd0 + i * 32);
        f32x4 acc[4];
        #pragma unroll
        for (int q = 0; q < 4; ++q)
            acc[q] = (gp == 0) ? biasD4[q] : (f32x4){0.f, 0.f, 0.f, 0.f};
        #pragma unroll
        for (int i = 0; i < 8; ++i)
            #pragma unroll
            for (int q = 0; q < 4; ++q)
                acc[q] = __builtin_amdgcn_mfma_f32_16x16x32_bf16(Breg[q * 8 + i], a[i], acc[q], 0, 0, 0);
        if (gp == 1) {
            #pragma unroll
            for (int q = 0; q < 4; ++q)
                Ex[par][q][bh][lane] = acc[q];
        }
        __syncthreads();
        if (gp == 0)
            cell_store(acc, cacc, Ex[par], flags, g, jt, bh, lane, arow, jq0,
                       (u32)(t + 1), Hdec + (size_t)(t - TIN) * BATCH * HID);
    }
}

// ---------------------------------------------------------------------------
// Final projection: out[b,t,f] = sum_j Hdec[t][b][j] * Wlin[f][j]
__global__ __launch_bounds__(128)
void final_proj_kernel(const bf16_t* __restrict__ Hdec, const bf16_t* __restrict__ Wlin,
                       float* __restrict__ out) {
    int tid = threadIdx.x;
    int wv = tid >> 6, lane = tid & 63;
    int l15 = lane & 15, l4 = lane >> 4;
    int row0 = blockIdx.x * 32 + wv * 16;
    const bf16_t* arow = Hdec + (size_t)(row0 + l15) * HID;
    f32x4 acc[8];
    #pragma unroll
    for (int n = 0; n < 8; ++n) acc[n] = (f32x4){0.f, 0.f, 0.f, 0.f};
    #pragma unroll 4
    for (int kc = 0; kc < HID; kc += 32) {
        bf16x8 af = *(const bf16x8*)(arow + kc + l4 * 8);
        #pragma unroll
        for (int n = 0; n < 8; ++n) {
            bf16x8 bfr = *(const bf16x8*)(Wlin + (size_t)(n * 16 + l15) * HID + kc + l4 * 8);
            acc[n] = __builtin_amdgcn_mfma_f32_16x16x32_bf16(af, bfr, acc[n], 0, 0, 0);
        }
    }
    #pragma unroll
    for (int n = 0; n < 8; ++n) {
        int f = n * 16 + l15;
        #pragma unroll
        for (int r = 0; r < 4; ++r) {
            int row = row0 + l4 * 4 + r;
            int t = row >> 8;
            int b = row & 255;
            out[(size_t)b * (TOUT * FEAT) + (size_t)t * FEAT + f] = acc[n][r];
        }
    }
}

// ---------------------------------------------------------------------------
extern "C" void kernel_launch(void* const* d_in, const int* in_sizes, int n_in,
                              void* d_out, int out_size, void* d_ws, size_t ws_size,
                              hipStream_t stream) {
    const float* x       = (const float*)d_in[0];
    const float* enc_Wih = (const float*)d_in[1];
    const float* enc_Whh = (const float*)d_in[2];
    const float* enc_b   = (const float*)d_in[3];
    const float* dec_Wih = (const float*)d_in[4];
    const float* dec_Whh = (const float*)d_in[5];
    const float* dec_b   = (const float*)d_in[6];
    const float* W_lin   = (const float*)d_in[7];
    float* out = (float*)d_out;

    char* p = (char*)d_ws;
    auto alloc = [&](size_t bytes) -> void* {
        void* r = (void*)p;
        p += (bytes + 255) & ~(size_t)255;
        return r;
    };
    bf16_t* Xbf    = (bf16_t*)alloc((size_t)TIN * BATCH * FEAT * 2);   // 11 MB
    bf16_t* Wenc   = (bf16_t*)alloc((size_t)2048 * 640 * 2);           // 2.6 MB
    bf16_t* Wdec1  = (bf16_t*)alloc((size_t)2048 * 640 * 2);           // 2.6 MB
    bf16_t* Wcomb  = (bf16_t*)alloc((size_t)2048 * HID * 2);           // 2.1 MB
    bf16_t* Wlinb  = (bf16_t*)alloc((size_t)FEAT * HID * 2);           // 128 KB
    bf16_t* hbufA  = (bf16_t*)alloc((size_t)BATCH * HID * 2);          // 256 KB
    bf16_t* hbufB  = (bf16_t*)alloc((size_t)BATCH * HID * 2);          // 256 KB
    bf16_t* Hdec   = (bf16_t*)alloc((size_t)TOUT * BATCH * HID * 2);   // 12.6 MB
    u32* flags     = (u32*)alloc((size_t)NGRP * 64 * 4);               // 2 KB

    // per-launch state init (replay-safe)
    (void)hipMemsetAsync(hbufA, 0, (size_t)BATCH * HID * 2, stream);
    (void)hipMemsetAsync(flags, 0, (size_t)NGRP * 64 * 4, stream);

    // precompute
    cast_x_kernel<<<(BATCH * TIN * (FEAT / 4) + 255) / 256, 256, 0, stream>>>(x, Xbf);
    cast_wcat_kernel<<<(2048 * 160 + 255) / 256, 256, 0, stream>>>(enc_Wih, enc_Whh, Wenc);
    cast_wcat_kernel<<<(2048 * 160 + 255) / 256, 256, 0, stream>>>(dec_Wih, dec_Whh, Wdec1);
    cast_wlin_kernel<<<(FEAT * HID / 4 + 255) / 256, 256, 0, stream>>>(W_lin, Wlinb);
    build_wcomb_kernel<<<dim3(2048 / 64, HID / 64), 256, 0, stream>>>(dec_Wih, dec_Whh, W_lin, Wcomb);

    // all 216 recurrent steps in one persistent kernel
    lstm_persist<<<NGRP * NJT, 256, 0, stream>>>(Xbf, Wenc, enc_b, Wdec1, Wcomb, dec_b,
                                                 hbufA, hbufB, Hdec, flags);

    // batched output projection (48 x 256 rows @ W_lin^T)
    final_proj_kernel<<<(TOUT * BATCH) / 32, 128, 0, stream>>>(Hdec, Wlinb, out);
}

// Round 13
// 1524.492 us; speedup vs baseline: 1.2307x; 1.2208x over previous
//
#include <hip/hip_runtime.h>
#include <hip/hip_bf16.h>

typedef __bf16 bf16_t;
typedef __bf16 bf16x8 __attribute__((ext_vector_type(8)));
typedef __bf16 bf16x4 __attribute__((ext_vector_type(4)));
typedef float  f32x4  __attribute__((ext_vector_type(4)));
typedef unsigned int u32;
typedef unsigned long long u64;

#define HID 512
#define BATCH 256
#define TIN 168
#define TOUT 48
#define FEAT 128
#define NSTEPS (TIN + TOUT)   // 216
#define NGRP 8                // batch groups
#define NJT 16                // blocks per group (j-tiles of 32 cols)
#define GRPB 32               // batch rows per group

__device__ __forceinline__ float sigmoidf_(float x) {
    x = fminf(fmaxf(x, -30.f), 30.f);
    return 1.f / (1.f + __expf(-x));
}
__device__ __forceinline__ float tanhf_(float x) {
    x = fminf(fmaxf(x, -15.f), 15.f);
    float e = __expf(2.f * x);
    return (e - 1.f) / (e + 1.f);
}

// Coherent IC-through primitives (R4/R10-proven): RELAXED system-scope atomics
// compile to global_load/store ... sc0 sc1 — no cache-maintenance ops.
__device__ __forceinline__ bf16x8 ld_h8(const bf16_t* p) {
    union { u64 q[2]; bf16x8 v; } u;
    u.q[0] = __hip_atomic_load((const u64*)p,     __ATOMIC_RELAXED,
                               __HIP_MEMORY_SCOPE_SYSTEM);
    u.q[1] = __hip_atomic_load((const u64*)p + 1, __ATOMIC_RELAXED,
                               __HIP_MEMORY_SCOPE_SYSTEM);
    return u.v;
}
// one 8B store of 4 consecutive bf16 h-values
__device__ __forceinline__ void st_h4(bf16_t* p, float v0, float v1, float v2, float v3) {
    bf16_t b0 = (bf16_t)v0, b1 = (bf16_t)v1, b2 = (bf16_t)v2, b3 = (bf16_t)v3;
    unsigned short s0, s1, s2, s3;
    __builtin_memcpy(&s0, &b0, 2); __builtin_memcpy(&s1, &b1, 2);
    __builtin_memcpy(&s2, &b2, 2); __builtin_memcpy(&s3, &b3, 2);
    u64 w = (u64)s0 | ((u64)s1 << 16) | ((u64)s2 << 32) | ((u64)s3 << 48);
    __hip_atomic_store((u64*)p, w, __ATOMIC_RELAXED, __HIP_MEMORY_SCOPE_SYSTEM);
}

// ---------------------------------------------------------------------------
// Cast x (B,T,F) fp32 -> Xbf (T,B,F) bf16
__global__ __launch_bounds__(256)
void cast_x_kernel(const float* __restrict__ x, bf16_t* __restrict__ Xbf) {
    int q = blockIdx.x * 256 + threadIdx.x;
    if (q >= BATCH * TIN * (FEAT / 4)) return;
    int f4  = q & 31;
    int rem = q >> 5;
    int t = rem % TIN;
    int b = rem / TIN;
    float4 v = *(const float4*)&x[((size_t)b * TIN + t) * FEAT + f4 * 4];
    bf16x4 o = { (bf16_t)v.x, (bf16_t)v.y, (bf16_t)v.z, (bf16_t)v.w };
    *(bf16x4*)&Xbf[((size_t)t * BATCH + b) * FEAT + f4 * 4] = o;
}

// Build Wcat (2048 x 640) bf16 = [Wih | Whh]
__global__ __launch_bounds__(256)
void cast_wcat_kernel(const float* __restrict__ Wih, const float* __restrict__ Whh,
                      bf16_t* __restrict__ Wcat) {
    int q = blockIdx.x * 256 + threadIdx.x;
    int k4 = q % 160;
    int r  = q / 160;
    if (r >= 2048) return;
    int k = k4 * 4;
    float4 v;
    if (k < FEAT) v = *(const float4*)&Wih[(size_t)r * FEAT + k];
    else          v = *(const float4*)&Whh[(size_t)r * HID + (k - FEAT)];
    bf16x4 o = { (bf16_t)v.x, (bf16_t)v.y, (bf16_t)v.z, (bf16_t)v.w };
    *(bf16x4*)&Wcat[(size_t)r * 640 + k] = o;
}

// Cast W_lin (128 x 512) fp32 -> bf16
__global__ __launch_bounds__(256)
void cast_wlin_kernel(const float* __restrict__ W, bf16_t* __restrict__ Wb) {
    int q = blockIdx.x * 256 + threadIdx.x;
    if (q >= FEAT * HID / 4) return;
    float4 v = *(const float4*)&W[q * 4];
    bf16x4 o = { (bf16_t)v.x, (bf16_t)v.y, (bf16_t)v.z, (bf16_t)v.w };
    *(bf16x4*)&Wb[q * 4] = o;
}

// Wcomb (2048 x 512) = dec_Wih (2048x128) @ W_lin (128x512) + dec_Whh, bf16 out
__global__ __launch_bounds__(256)
void build_wcomb_kernel(const float* __restrict__ dWih, const float* __restrict__ dWhh,
                        const float* __restrict__ Wlin, bf16_t* __restrict__ Wcomb) {
    __shared__ float As[64][128];
    __shared__ float Bs[128][64];
    int r0 = blockIdx.x * 64, c0 = blockIdx.y * 64;
    int tid = threadIdx.x;
    for (int i = tid; i < 64 * 32; i += 256) {
        int rr = i >> 5, cc = (i & 31) << 2;
        *(float4*)&As[rr][cc] = *(const float4*)&dWih[(size_t)(r0 + rr) * 128 + cc];
    }
    for (int i = tid; i < 128 * 16; i += 256) {
        int kk = i >> 4, cc = (i & 15) << 2;
        *(float4*)&Bs[kk][cc] = *(const float4*)&Wlin[(size_t)kk * HID + c0 + cc];
    }
    __syncthreads();
    int tx = tid & 15, ty = tid >> 4;
    float acc[4][4] = {};
    for (int k = 0; k < 128; ++k) {
        float a[4], b[4];
        #pragma unroll
        for (int i = 0; i < 4; ++i) a[i] = As[ty * 4 + i][k];
        #pragma unroll
        for (int j = 0; j < 4; ++j) b[j] = Bs[k][tx * 4 + j];
        #pragma unroll
        for (int i = 0; i < 4; ++i)
            #pragma unroll
            for (int j = 0; j < 4; ++j) acc[i][j] += a[i] * b[j];
    }
    for (int i = 0; i < 4; ++i) {
        int r = r0 + ty * 4 + i;
        for (int j = 0; j < 4; ++j) {
            int cc = c0 + tx * 4 + j;
            Wcomb[(size_t)r * HID + cc] = (bf16_t)(acc[i][j] + dWhh[(size_t)r * HID + cc]);
        }
    }
}

// ---------------------------------------------------------------------------
// Persistent seq2seq LSTM — R10 protocol, 16 blocks/group x 8 waves.
// 128 blocks x 512 threads. Block -> (g = bid&7, jt = bid>>3, 32 hidden cols).
// Wave = (gp, bh, ch): ch = wave&1 (col 16-half), bh = (wave>>1)&1 (batch
// half), gp = wave>>2 (K half). Each wave = exactly an R10 wave's workload
// at jbase = jt*32 + ch*16. Weights pinned in regs; c register-resident.
// Swapped mfma(W, xh): lane owns batch row b0+l15, 4 consecutive hidden cols.
// Protocol (R10-proven): single flag per block; wave-0 16-lane poll +
// syncthreads; gp1 -> Ex; barrier; gp0 merge+cell+8B-store+drain; barrier;
// tid0 flag. Halved h-replication: 4 MB/step IC reads (was 8).

__device__ __forceinline__ void group_wait(const u32* flags, int g, int tid,
                                           u32 epoch) {
    if (tid < NJT) {
        while (__hip_atomic_load(&flags[g * NJT + tid], __ATOMIC_RELAXED,
                                 __HIP_MEMORY_SCOPE_SYSTEM) < epoch)
            __builtin_amdgcn_s_sleep(1);
    }
    __syncthreads();
}

__device__ __forceinline__ void group_arrive(u32* flags, int g, int jt, int tid,
                                             u32 epoch) {
    if (tid == 0)
        __hip_atomic_store(&flags[g * NJT + jt], epoch, __ATOMIC_RELAXED,
                           __HIP_MEMORY_SCOPE_SYSTEM);
}

// gp1 -> Ex; barrier; gp0: merge, cell, packed store, drain; barrier.
__device__ __forceinline__ void cell_finish(
    f32x4 (&acc)[4], float (&cacc)[4], f32x4 (*Ex)[4][64],
    int gp, int sub, int lane, int brow, int jq0,
    bf16_t* __restrict__ hnext)
{
    if (gp == 1) {
        #pragma unroll
        for (int q = 0; q < 4; ++q)
            Ex[q][sub][lane] = acc[q];
    }
    __syncthreads();
    if (gp == 0) {
        #pragma unroll
        for (int q = 0; q < 4; ++q)
            acc[q] += Ex[q][sub][lane];
        float hv[4];
        #pragma unroll
        for (int r = 0; r < 4; ++r) {
            float cn = sigmoidf_(acc[1][r]) * cacc[r] + sigmoidf_(acc[0][r]) * tanhf_(acc[2][r]);
            cacc[r] = cn;
            hv[r] = sigmoidf_(acc[3][r]) * tanhf_(cn);
        }
        st_h4(hnext + (size_t)brow * HID + jq0, hv[0], hv[1], hv[2], hv[3]);
        asm volatile("s_waitcnt vmcnt(0)" ::: "memory");   // h acked at IC
    }
    __syncthreads();
}

__global__ __launch_bounds__(512, 1)
void lstm_persist(const bf16_t* __restrict__ Xbf,
                  const bf16_t* __restrict__ Wenc, const float* __restrict__ enc_b,
                  const bf16_t* __restrict__ Wdec1, const bf16_t* __restrict__ Wcomb,
                  const float* __restrict__ dec_b,
                  bf16_t* __restrict__ hbufA, bf16_t* __restrict__ hbufB,
                  bf16_t* __restrict__ Hdec, u32* __restrict__ flags)
{
    __shared__ f32x4 Ex[4][4][64];     // gate x (bh,ch) x lane, 16 KB
    const int bid = blockIdx.x;
    const int g   = bid & (NGRP - 1);
    const int jt  = bid >> 3;          // 0..15
    const int j0  = jt * 32;
    const int tid = threadIdx.x;
    const int wave = tid >> 6, lane = tid & 63;
    const int l15 = lane & 15, l4 = lane >> 4;
    const int ch = wave & 1, bh = (wave >> 1) & 1, gp = wave >> 2;
    const int sub = bh * 2 + ch;       // Ex slot
    const int jbase = j0 + ch * 16;
    const int b0 = g * GRPB + bh * 16;
    const int arow = b0 + l15;          // batch row this lane owns (B-operand)
    const int jcol = jbase + l15;       // W row for fragment load (A-operand)
    const int jq0  = jbase + l4 * 4;    // first of this lane's 4 hidden cols

    f32x4 biasE4[4], biasD4[4];
    #pragma unroll
    for (int q = 0; q < 4; ++q) {
        biasE4[q] = *(const f32x4*)&enc_b[q * HID + jq0];
        biasD4[q] = *(const f32x4*)&dec_b[q * HID + jq0];
    }
    float cacc[4] = {0.f, 0.f, 0.f, 0.f};

    bf16x8 Breg[40];
    const int kc0 = gp * 320;    // K-half base for K=640 phases

    // ---- encoder weight fragments (K=640), pinned
    #pragma unroll
    for (int q = 0; q < 4; ++q)
        #pragma unroll
        for (int i = 0; i < 10; ++i)
            Breg[q * 10 + i] = *(const bf16x8*)(
                Wenc + (size_t)(q * HID + jcol) * 640 + kc0 + i * 32 + l4 * 8);
    #pragma unroll
    for (int n = 0; n < 40; ++n) asm volatile("" : "+v"(Breg[n]));

    // ================= encoder: t = 0..167 =================
    for (int t = 0; t < TIN; ++t) {
        if (t > 0) group_wait(flags, g, tid, (u32)t);
        const bf16_t* hb = (t & 1) ? hbufB : hbufA;
        bf16_t* hn       = (t & 1) ? hbufA : hbufB;
        const bf16_t* xb  = Xbf + ((size_t)t * BATCH + arow) * FEAT + l4 * 8;
        const bf16_t* hbp = hb + (size_t)arow * HID + l4 * 8;
        bf16x8 a[10];
        if (gp == 0) {
            #pragma unroll
            for (int i = 0; i < 4; ++i)  a[i] = *(const bf16x8*)(xb + i * 32);
            #pragma unroll
            for (int i = 4; i < 10; ++i) a[i] = ld_h8(hbp + (i * 32 - FEAT));
        } else {
            #pragma unroll
            for (int i = 0; i < 10; ++i) a[i] = ld_h8(hbp + (320 - FEAT) + i * 32);
        }
        f32x4 acc[4];
        #pragma unroll
        for (int q = 0; q < 4; ++q)
            acc[q] = (gp == 0) ? biasE4[q] : (f32x4){0.f, 0.f, 0.f, 0.f};
        #pragma unroll
        for (int i = 0; i < 10; ++i)
            #pragma unroll
            for (int q = 0; q < 4; ++q)
                acc[q] = __builtin_amdgcn_mfma_f32_16x16x32_bf16(Breg[q * 10 + i], a[i], acc[q], 0, 0, 0);
        cell_finish(acc, cacc, Ex, gp, sub, lane, arow, jq0, hn);
        group_arrive(flags, g, jt, tid, (u32)(t + 1));
    }

    // ---- decoder step 0 weights (Wdec1, K=640)
    #pragma unroll
    for (int q = 0; q < 4; ++q)
        #pragma unroll
        for (int i = 0; i < 10; ++i)
            Breg[q * 10 + i] = *(const bf16x8*)(
                Wdec1 + (size_t)(q * HID + jcol) * 640 + kc0 + i * 32 + l4 * 8);
    #pragma unroll
    for (int n = 0; n < 40; ++n) asm volatile("" : "+v"(Breg[n]));

    // ================= decoder step 0: t = 168 =================
    {
        const int t = TIN;
        group_wait(flags, g, tid, (u32)t);
        // h_168 lives in hbufA (written at t=167)
        const bf16_t* xb  = Xbf + ((size_t)(TIN - 1) * BATCH + arow) * FEAT + l4 * 8;
        const bf16_t* hbp = hbufA + (size_t)arow * HID + l4 * 8;
        bf16x8 a[10];
        if (gp == 0) {
            #pragma unroll
            for (int i = 0; i < 4; ++i)  a[i] = *(const bf16x8*)(xb + i * 32);
            #pragma unroll
            for (int i = 4; i < 10; ++i) a[i] = ld_h8(hbp + (i * 32 - FEAT));
        } else {
            #pragma unroll
            for (int i = 0; i < 10; ++i) a[i] = ld_h8(hbp + (320 - FEAT) + i * 32);
        }
        f32x4 acc[4];
        #pragma unroll
        for (int q = 0; q < 4; ++q)
            acc[q] = (gp == 0) ? biasD4[q] : (f32x4){0.f, 0.f, 0.f, 0.f};
        #pragma unroll
        for (int i = 0; i < 10; ++i)
            #pragma unroll
            for (int q = 0; q < 4; ++q)
                acc[q] = __builtin_amdgcn_mfma_f32_16x16x32_bf16(Breg[q * 10 + i], a[i], acc[q], 0, 0, 0);
        cell_finish(acc, cacc, Ex, gp, sub, lane, arow, jq0, Hdec);
        group_arrive(flags, g, jt, tid, (u32)(t + 1));
    }

    // ---- folded decoder weights (Wcomb, K=512)
    const int kd0 = gp * 256;
    #pragma unroll
    for (int q = 0; q < 4; ++q)
        #pragma unroll
        for (int i = 0; i < 8; ++i)
            Breg[q * 8 + i] = *(const bf16x8*)(
                Wcomb + (size_t)(q * HID + jcol) * HID + kd0 + i * 32 + l4 * 8);
    #pragma unroll
    for (int n = 0; n < 32; ++n) asm volatile("" : "+v"(Breg[n]));

    // ================= decoder: t = 169..215 =================
    for (int t = TIN + 1; t < NSTEPS; ++t) {
        group_wait(flags, g, tid, (u32)t);
        const bf16_t* hprev = Hdec + (size_t)(t - 1 - TIN) * BATCH * HID
                                   + (size_t)arow * HID + l4 * 8;
        bf16x8 a[8];
        #pragma unroll
        for (int i = 0; i < 8; ++i)
            a[i] = ld_h8(hprev + kd0 + i * 32);
        f32x4 acc[4];
        #pragma unroll
        for (int q = 0; q < 4; ++q)
            acc[q] = (gp == 0) ? biasD4[q] : (f32x4){0.f, 0.f, 0.f, 0.f};
        #pragma unroll
        for (int i = 0; i < 8; ++i)
            #pragma unroll
            for (int q = 0; q < 4; ++q)
                acc[q] = __builtin_amdgcn_mfma_f32_16x16x32_bf16(Breg[q * 8 + i], a[i], acc[q], 0, 0, 0);
        cell_finish(acc, cacc, Ex, gp, sub, lane, arow, jq0,
                    Hdec + (size_t)(t - TIN) * BATCH * HID);
        group_arrive(flags, g, jt, tid, (u32)(t + 1));
    }
}

// ---------------------------------------------------------------------------
// Final projection: out[b,t,f] = sum_j Hdec[t][b][j] * Wlin[f][j]
__global__ __launch_bounds__(128)
void final_proj_kernel(const bf16_t* __restrict__ Hdec, const bf16_t* __restrict__ Wlin,
                       float* __restrict__ out) {
    int tid = threadIdx.x;
    int wv = tid >> 6, lane = tid & 63;
    int l15 = lane & 15, l4 = lane >> 4;
    int row0 = blockIdx.x * 32 + wv * 16;
    const bf16_t* arow = Hdec + (size_t)(row0 + l15) * HID;
    f32x4 acc[8];
    #pragma unroll
    for (int n = 0; n < 8; ++n) acc[n] = (f32x4){0.f, 0.f, 0.f, 0.f};
    #pragma unroll 4
    for (int kc = 0; kc < HID; kc += 32) {
        bf16x8 af = *(const bf16x8*)(arow + kc + l4 * 8);
        #pragma unroll
        for (int n = 0; n < 8; ++n) {
            bf16x8 bfr = *(const bf16x8*)(Wlin + (size_t)(n * 16 + l15) * HID + kc + l4 * 8);
            acc[n] = __builtin_amdgcn_mfma_f32_16x16x32_bf16(af, bfr, acc[n], 0, 0, 0);
        }
    }
    #pragma unroll
    for (int n = 0; n < 8; ++n) {
        int f = n * 16 + l15;
        #pragma unroll
        for (int r = 0; r < 4; ++r) {
            int row = row0 + l4 * 4 + r;
            int t = row >> 8;
            int b = row & 255;
            out[(size_t)b * (TOUT * FEAT) + (size_t)t * FEAT + f] = acc[n][r];
        }
    }
}

// ---------------------------------------------------------------------------
extern "C" void kernel_launch(void* const* d_in, const int* in_sizes, int n_in,
                              void* d_out, int out_size, void* d_ws, size_t ws_size,
                              hipStream_t stream) {
    const float* x       = (const float*)d_in[0];
    const float* enc_Wih = (const float*)d_in[1];
    const float* enc_Whh = (const float*)d_in[2];
    const float* enc_b   = (const float*)d_in[3];
    const float* dec_Wih = (const float*)d_in[4];
    const float* dec_Whh = (const float*)d_in[5];
    const float* dec_b   = (const float*)d_in[6];
    const float* W_lin   = (const float*)d_in[7];
    float* out = (float*)d_out;

    char* p = (char*)d_ws;
    auto alloc = [&](size_t bytes) -> void* {
        void* r = (void*)p;
        p += (bytes + 255) & ~(size_t)255;
        return r;
    };
    bf16_t* Xbf    = (bf16_t*)alloc((size_t)TIN * BATCH * FEAT * 2);   // 11 MB
    bf16_t* Wenc   = (bf16_t*)alloc((size_t)2048 * 640 * 2);           // 2.6 MB
    bf16_t* Wdec1  = (bf16_t*)alloc((size_t)2048 * 640 * 2);           // 2.6 MB
    bf16_t* Wcomb  = (bf16_t*)alloc((size_t)2048 * HID * 2);           // 2.1 MB
    bf16_t* Wlinb  = (bf16_t*)alloc((size_t)FEAT * HID * 2);           // 128 KB
    bf16_t* hbufA  = (bf16_t*)alloc((size_t)BATCH * HID * 2);          // 256 KB
    bf16_t* hbufB  = (bf16_t*)alloc((size_t)BATCH * HID * 2);          // 256 KB
    bf16_t* Hdec   = (bf16_t*)alloc((size_t)TOUT * BATCH * HID * 2);   // 12.6 MB
    u32* flags     = (u32*)alloc((size_t)NGRP * NJT * 4);              // 512 B

    // per-launch state init (replay-safe)
    (void)hipMemsetAsync(hbufA, 0, (size_t)BATCH * HID * 2, stream);
    (void)hipMemsetAsync(flags, 0, (size_t)NGRP * NJT * 4, stream);

    // precompute
    cast_x_kernel<<<(BATCH * TIN * (FEAT / 4) + 255) / 256, 256, 0, stream>>>(x, Xbf);
    cast_wcat_kernel<<<(2048 * 160 + 255) / 256, 256, 0, stream>>>(enc_Wih, enc_Whh, Wenc);
    cast_wcat_kernel<<<(2048 * 160 + 255) / 256, 256, 0, stream>>>(dec_Wih, dec_Whh, Wdec1);
    cast_wlin_kernel<<<(FEAT * HID / 4 + 255) / 256, 256, 0, stream>>>(W_lin, Wlinb);
    build_wcomb_kernel<<<dim3(2048 / 64, HID / 64), 256, 0, stream>>>(dec_Wih, dec_Whh, W_lin, Wcomb);

    // all 216 recurrent steps in one persistent kernel (128 blocks x 512 thr)
    lstm_persist<<<NGRP * NJT, 512, 0, stream>>>(Xbf, Wenc, enc_b, Wdec1, Wcomb, dec_b,
                                                 hbufA, hbufB, Hdec, flags);

    // batched output projection (48 x 256 rows @ W_lin^T)
    final_proj_kernel<<<(TOUT * BATCH) / 32, 128, 0, stream>>>(Hdec, Wlinb, out);
}

// Round 14
// 1409.480 us; speedup vs baseline: 1.3311x; 1.0816x over previous
//
#include <hip/hip_runtime.h>
#include <hip/hip_bf16.h>

typedef __bf16 bf16_t;
typedef __bf16 bf16x8 __attribute__((ext_vector_type(8)));
typedef __bf16 bf16x4 __attribute__((ext_vector_type(4)));
typedef float  f32x4  __attribute__((ext_vector_type(4)));
typedef unsigned int u32;
typedef unsigned long long u64;

#define HID 512
#define BATCH 256
#define TIN 168
#define TOUT 48
#define FEAT 128
#define NSTEPS (TIN + TOUT)   // 216
#define NGRP 16               // batch groups (16 rows each)
#define NJB 8                 // blocks per group (64 cols each)
#define GRPB 16               // batch rows per group

__device__ __forceinline__ float sigmoidf_(float x) {
    x = fminf(fmaxf(x, -30.f), 30.f);
    return 1.f / (1.f + __expf(-x));
}
__device__ __forceinline__ float tanhf_(float x) {
    x = fminf(fmaxf(x, -15.f), 15.f);
    float e = __expf(2.f * x);
    return (e - 1.f) / (e + 1.f);
}

// Coherent IC-through primitives (R4/R10-proven): RELAXED system-scope atomics
// compile to global_load/store ... sc0 sc1 — no cache-maintenance ops.
__device__ __forceinline__ bf16x8 ld_h8(const bf16_t* p) {
    union { u64 q[2]; bf16x8 v; } u;
    u.q[0] = __hip_atomic_load((const u64*)p,     __ATOMIC_RELAXED,
                               __HIP_MEMORY_SCOPE_SYSTEM);
    u.q[1] = __hip_atomic_load((const u64*)p + 1, __ATOMIC_RELAXED,
                               __HIP_MEMORY_SCOPE_SYSTEM);
    return u.v;
}
// one 8B store of 4 consecutive bf16 h-values
__device__ __forceinline__ void st_h4(bf16_t* p, float v0, float v1, float v2, float v3) {
    bf16_t b0 = (bf16_t)v0, b1 = (bf16_t)v1, b2 = (bf16_t)v2, b3 = (bf16_t)v3;
    unsigned short s0, s1, s2, s3;
    __builtin_memcpy(&s0, &b0, 2); __builtin_memcpy(&s1, &b1, 2);
    __builtin_memcpy(&s2, &b2, 2); __builtin_memcpy(&s3, &b3, 2);
    u64 w = (u64)s0 | ((u64)s1 << 16) | ((u64)s2 << 32) | ((u64)s3 << 48);
    __hip_atomic_store((u64*)p, w, __ATOMIC_RELAXED, __HIP_MEMORY_SCOPE_SYSTEM);
}

// ---------------------------------------------------------------------------
// Cast x (B,T,F) fp32 -> Xbf (T,B,F) bf16
__global__ __launch_bounds__(256)
void cast_x_kernel(const float* __restrict__ x, bf16_t* __restrict__ Xbf) {
    int q = blockIdx.x * 256 + threadIdx.x;
    if (q >= BATCH * TIN * (FEAT / 4)) return;
    int f4  = q & 31;
    int rem = q >> 5;
    int t = rem % TIN;
    int b = rem / TIN;
    float4 v = *(const float4*)&x[((size_t)b * TIN + t) * FEAT + f4 * 4];
    bf16x4 o = { (bf16_t)v.x, (bf16_t)v.y, (bf16_t)v.z, (bf16_t)v.w };
    *(bf16x4*)&Xbf[((size_t)t * BATCH + b) * FEAT + f4 * 4] = o;
}

// Build Wcat (2048 x 640) bf16 = [Wih | Whh]
__global__ __launch_bounds__(256)
void cast_wcat_kernel(const float* __restrict__ Wih, const float* __restrict__ Whh,
                      bf16_t* __restrict__ Wcat) {
    int q = blockIdx.x * 256 + threadIdx.x;
    int k4 = q % 160;
    int r  = q / 160;
    if (r >= 2048) return;
    int k = k4 * 4;
    float4 v;
    if (k < FEAT) v = *(const float4*)&Wih[(size_t)r * FEAT + k];
    else          v = *(const float4*)&Whh[(size_t)r * HID + (k - FEAT)];
    bf16x4 o = { (bf16_t)v.x, (bf16_t)v.y, (bf16_t)v.z, (bf16_t)v.w };
    *(bf16x4*)&Wcat[(size_t)r * 640 + k] = o;
}

// Cast W_lin (128 x 512) fp32 -> bf16
__global__ __launch_bounds__(256)
void cast_wlin_kernel(const float* __restrict__ W, bf16_t* __restrict__ Wb) {
    int q = blockIdx.x * 256 + threadIdx.x;
    if (q >= FEAT * HID / 4) return;
    float4 v = *(const float4*)&W[q * 4];
    bf16x4 o = { (bf16_t)v.x, (bf16_t)v.y, (bf16_t)v.z, (bf16_t)v.w };
    *(bf16x4*)&Wb[q * 4] = o;
}

// Wcomb (2048 x 512) = dec_Wih (2048x128) @ W_lin (128x512) + dec_Whh, bf16 out
__global__ __launch_bounds__(256)
void build_wcomb_kernel(const float* __restrict__ dWih, const float* __restrict__ dWhh,
                        const float* __restrict__ Wlin, bf16_t* __restrict__ Wcomb) {
    __shared__ float As[64][128];
    __shared__ float Bs[128][64];
    int r0 = blockIdx.x * 64, c0 = blockIdx.y * 64;
    int tid = threadIdx.x;
    for (int i = tid; i < 64 * 32; i += 256) {
        int rr = i >> 5, cc = (i & 31) << 2;
        *(float4*)&As[rr][cc] = *(const float4*)&dWih[(size_t)(r0 + rr) * 128 + cc];
    }
    for (int i = tid; i < 128 * 16; i += 256) {
        int kk = i >> 4, cc = (i & 15) << 2;
        *(float4*)&Bs[kk][cc] = *(const float4*)&Wlin[(size_t)kk * HID + c0 + cc];
    }
    __syncthreads();
    int tx = tid & 15, ty = tid >> 4;
    float acc[4][4] = {};
    for (int k = 0; k < 128; ++k) {
        float a[4], b[4];
        #pragma unroll
        for (int i = 0; i < 4; ++i) a[i] = As[ty * 4 + i][k];
        #pragma unroll
        for (int j = 0; j < 4; ++j) b[j] = Bs[k][tx * 4 + j];
        #pragma unroll
        for (int i = 0; i < 4; ++i)
            #pragma unroll
            for (int j = 0; j < 4; ++j) acc[i][j] += a[i] * b[j];
    }
    for (int i = 0; i < 4; ++i) {
        int r = r0 + ty * 4 + i;
        for (int j = 0; j < 4; ++j) {
            int cc = c0 + tx * 4 + j;
            Wcomb[(size_t)r * HID + cc] = (bf16_t)(acc[i][j] + dWhh[(size_t)r * HID + cc]);
        }
    }
}

// ---------------------------------------------------------------------------
// Persistent seq2seq LSTM — full-K-per-wave, no intra-block exchange.
// 128 blocks x 256 threads. Block -> (g = bid&15 batch group of 16 rows,
// jb = bid>>4 col block of 64). Wave w owns cols jb*64 + w*16 with the
// ENTIRE K dimension register-resident (80 frags = 320 VGPR) -> complete
// gates in-wave: no Ex, no K-merge, no wave roles. Swapped mfma(W, xh):
// lane owns batch row g*16+l15, 4 consecutive hidden cols -> one 8B h store.
// Protocol (R10-proven atoms): 1 flag/block; tid<8 poll + barrier; all waves
// compute+store+drain; barrier; tid0 flag.

__device__ __forceinline__ void group_wait(const u32* flags, int g, int tid,
                                           u32 epoch) {
    if (tid < NJB) {
        while (__hip_atomic_load(&flags[g * NJB + tid], __ATOMIC_RELAXED,
                                 __HIP_MEMORY_SCOPE_SYSTEM) < epoch)
            __builtin_amdgcn_s_sleep(1);
    }
    __syncthreads();
}

__device__ __forceinline__ void group_arrive(u32* flags, int g, int jb, int tid,
                                             u32 epoch) {
    __syncthreads();   // all waves drained their h stores
    if (tid == 0)
        __hip_atomic_store(&flags[g * NJB + jb], epoch, __ATOMIC_RELAXED,
                           __HIP_MEMORY_SCOPE_SYSTEM);
}

// complete-gate cell update + packed h store + drain (every wave)
__device__ __forceinline__ void cell_store(
    f32x4 (&acc)[4], float (&cacc)[4], int brow, int jq0,
    bf16_t* __restrict__ hnext)
{
    float hv[4];
    #pragma unroll
    for (int r = 0; r < 4; ++r) {
        float cn = sigmoidf_(acc[1][r]) * cacc[r] + sigmoidf_(acc[0][r]) * tanhf_(acc[2][r]);
        cacc[r] = cn;
        hv[r] = sigmoidf_(acc[3][r]) * tanhf_(cn);
    }
    st_h4(hnext + (size_t)brow * HID + jq0, hv[0], hv[1], hv[2], hv[3]);
    asm volatile("s_waitcnt vmcnt(0)" ::: "memory");   // h acked at IC
}

__global__ __launch_bounds__(256, 1)
void lstm_persist(const bf16_t* __restrict__ Xbf,
                  const bf16_t* __restrict__ Wenc, const float* __restrict__ enc_b,
                  const bf16_t* __restrict__ Wdec1, const bf16_t* __restrict__ Wcomb,
                  const float* __restrict__ dec_b,
                  bf16_t* __restrict__ hbufA, bf16_t* __restrict__ hbufB,
                  bf16_t* __restrict__ Hdec, u32* __restrict__ flags)
{
    const int bid = blockIdx.x;
    const int g   = bid & (NGRP - 1);   // batch group (16 rows)
    const int jb  = bid >> 4;           // col block (64 cols), 0..7
    const int tid = threadIdx.x;
    const int wave = tid >> 6, lane = tid & 63;
    const int l15 = lane & 15, l4 = lane >> 4;
    const int colbase = jb * 64 + wave * 16;   // this wave's 16 hidden cols
    const int arow = g * GRPB + l15;           // batch row this lane owns
    const int jcol = colbase + l15;            // W row within gate
    const int jq0  = colbase + l4 * 4;         // lane's 4 consecutive cols

    f32x4 biasE4[4], biasD4[4];
    #pragma unroll
    for (int q = 0; q < 4; ++q) {
        biasE4[q] = *(const f32x4*)&enc_b[q * HID + jq0];
        biasD4[q] = *(const f32x4*)&dec_b[q * HID + jq0];
    }
    float cacc[4] = {0.f, 0.f, 0.f, 0.f};

    bf16x8 Breg[80];   // 4 gates x 20 K-frags, 320 VGPR, full K=640

    // ---- encoder weight fragments (K=640), pinned
    #pragma unroll
    for (int q = 0; q < 4; ++q)
        #pragma unroll
        for (int i = 0; i < 20; ++i)
            Breg[q * 20 + i] = *(const bf16x8*)(
                Wenc + (size_t)(q * HID + jcol) * 640 + i * 32 + l4 * 8);
    #pragma unroll
    for (int n = 0; n < 80; ++n) asm volatile("" : "+v"(Breg[n]));

    // ================= encoder: t = 0..167 =================
    for (int t = 0; t < TIN; ++t) {
        bf16x8 a[20];
        // x prefetch (h-independent) before the wait
        const bf16_t* xb = Xbf + ((size_t)t * BATCH + arow) * FEAT + l4 * 8;
        #pragma unroll
        for (int i = 0; i < 4; ++i) a[i] = *(const bf16x8*)(xb + i * 32);
        if (t > 0) group_wait(flags, g, tid, (u32)t);
        const bf16_t* hb = (t & 1) ? hbufB : hbufA;
        bf16_t* hn       = (t & 1) ? hbufA : hbufB;
        const bf16_t* hbp = hb + (size_t)arow * HID + l4 * 8;
        #pragma unroll
        for (int i = 4; i < 20; ++i) a[i] = ld_h8(hbp + (i * 32 - FEAT));
        f32x4 acc[4];
        #pragma unroll
        for (int q = 0; q < 4; ++q) acc[q] = biasE4[q];
        #pragma unroll
        for (int i = 0; i < 20; ++i)
            #pragma unroll
            for (int q = 0; q < 4; ++q)
                acc[q] = __builtin_amdgcn_mfma_f32_16x16x32_bf16(Breg[q * 20 + i], a[i], acc[q], 0, 0, 0);
        cell_store(acc, cacc, arow, jq0, hn);
        group_arrive(flags, g, jb, tid, (u32)(t + 1));
    }

    // ---- decoder step 0 weights (Wdec1, K=640)
    #pragma unroll
    for (int q = 0; q < 4; ++q)
        #pragma unroll
        for (int i = 0; i < 20; ++i)
            Breg[q * 20 + i] = *(const bf16x8*)(
                Wdec1 + (size_t)(q * HID + jcol) * 640 + i * 32 + l4 * 8);
    #pragma unroll
    for (int n = 0; n < 80; ++n) asm volatile("" : "+v"(Breg[n]));

    // ================= decoder step 0: t = 168 =================
    {
        const int t = TIN;
        bf16x8 a[20];
        const bf16_t* xb = Xbf + ((size_t)(TIN - 1) * BATCH + arow) * FEAT + l4 * 8;
        #pragma unroll
        for (int i = 0; i < 4; ++i) a[i] = *(const bf16x8*)(xb + i * 32);
        group_wait(flags, g, tid, (u32)t);
        // h_168 lives in hbufA (written at t=167)
        const bf16_t* hbp = hbufA + (size_t)arow * HID + l4 * 8;
        #pragma unroll
        for (int i = 4; i < 20; ++i) a[i] = ld_h8(hbp + (i * 32 - FEAT));
        f32x4 acc[4];
        #pragma unroll
        for (int q = 0; q < 4; ++q) acc[q] = biasD4[q];
        #pragma unroll
        for (int i = 0; i < 20; ++i)
            #pragma unroll
            for (int q = 0; q < 4; ++q)
                acc[q] = __builtin_amdgcn_mfma_f32_16x16x32_bf16(Breg[q * 20 + i], a[i], acc[q], 0, 0, 0);
        cell_store(acc, cacc, arow, jq0, Hdec);
        group_arrive(flags, g, jb, tid, (u32)(t + 1));
    }

    // ---- folded decoder weights (Wcomb, K=512): 64 frags
    #pragma unroll
    for (int q = 0; q < 4; ++q)
        #pragma unroll
        for (int i = 0; i < 16; ++i)
            Breg[q * 16 + i] = *(const bf16x8*)(
                Wcomb + (size_t)(q * HID + jcol) * HID + i * 32 + l4 * 8);
    #pragma unroll
    for (int n = 0; n < 64; ++n) asm volatile("" : "+v"(Breg[n]));

    // ================= decoder: t = 169..215 =================
    for (int t = TIN + 1; t < NSTEPS; ++t) {
        group_wait(flags, g, tid, (u32)t);
        const bf16_t* hprev = Hdec + (size_t)(t - 1 - TIN) * BATCH * HID
                                   + (size_t)arow * HID + l4 * 8;
        bf16x8 a[16];
        #pragma unroll
        for (int i = 0; i < 16; ++i)
            a[i] = ld_h8(hprev + i * 32);
        f32x4 acc[4];
        #pragma unroll
        for (int q = 0; q < 4; ++q) acc[q] = biasD4[q];
        #pragma unroll
        for (int i = 0; i < 16; ++i)
            #pragma unroll
            for (int q = 0; q < 4; ++q)
                acc[q] = __builtin_amdgcn_mfma_f32_16x16x32_bf16(Breg[q * 16 + i], a[i], acc[q], 0, 0, 0);
        cell_store(acc, cacc, arow, jq0,
                   Hdec + (size_t)(t - TIN) * BATCH * HID);
        group_arrive(flags, g, jb, tid, (u32)(t + 1));
    }
}

// ---------------------------------------------------------------------------
// Final projection: out[b,t,f] = sum_j Hdec[t][b][j] * Wlin[f][j]
__global__ __launch_bounds__(128)
void final_proj_kernel(const bf16_t* __restrict__ Hdec, const bf16_t* __restrict__ Wlin,
                       float* __restrict__ out) {
    int tid = threadIdx.x;
    int wv = tid >> 6, lane = tid & 63;
    int l15 = lane & 15, l4 = lane >> 4;
    int row0 = blockIdx.x * 32 + wv * 16;
    const bf16_t* arow = Hdec + (size_t)(row0 + l15) * HID;
    f32x4 acc[8];
    #pragma unroll
    for (int n = 0; n < 8; ++n) acc[n] = (f32x4){0.f, 0.f, 0.f, 0.f};
    #pragma unroll 4
    for (int kc = 0; kc < HID; kc += 32) {
        bf16x8 af = *(const bf16x8*)(arow + kc + l4 * 8);
        #pragma unroll
        for (int n = 0; n < 8; ++n) {
            bf16x8 bfr = *(const bf16x8*)(Wlin + (size_t)(n * 16 + l15) * HID + kc + l4 * 8);
            acc[n] = __builtin_amdgcn_mfma_f32_16x16x32_bf16(af, bfr, acc[n], 0, 0, 0);
        }
    }
    #pragma unroll
    for (int n = 0; n < 8; ++n) {
        int f = n * 16 + l15;
        #pragma unroll
        for (int r = 0; r < 4; ++r) {
            int row = row0 + l4 * 4 + r;
            int t = row >> 8;
            int b = row & 255;
            out[(size_t)b * (TOUT * FEAT) + (size_t)t * FEAT + f] = acc[n][r];
        }
    }
}

// ---------------------------------------------------------------------------
extern "C" void kernel_launch(void* const* d_in, const int* in_sizes, int n_in,
                              void* d_out, int out_size, void* d_ws, size_t ws_size,
                              hipStream_t stream) {
    const float* x       = (const float*)d_in[0];
    const float* enc_Wih = (const float*)d_in[1];
    const float* enc_Whh = (const float*)d_in[2];
    const float* enc_b   = (const float*)d_in[3];
    const float* dec_Wih = (const float*)d_in[4];
    const float* dec_Whh = (const float*)d_in[5];
    const float* dec_b   = (const float*)d_in[6];
    const float* W_lin   = (const float*)d_in[7];
    float* out = (float*)d_out;

    char* p = (char*)d_ws;
    auto alloc = [&](size_t bytes) -> void* {
        void* r = (void*)p;
        p += (bytes + 255) & ~(size_t)255;
        return r;
    };
    bf16_t* Xbf    = (bf16_t*)alloc((size_t)TIN * BATCH * FEAT * 2);   // 11 MB
    bf16_t* Wenc   = (bf16_t*)alloc((size_t)2048 * 640 * 2);           // 2.6 MB
    bf16_t* Wdec1  = (bf16_t*)alloc((size_t)2048 * 640 * 2);           // 2.6 MB
    bf16_t* Wcomb  = (bf16_t*)alloc((size_t)2048 * HID * 2);           // 2.1 MB
    bf16_t* Wlinb  = (bf16_t*)alloc((size_t)FEAT * HID * 2);           // 128 KB
    bf16_t* hbufA  = (bf16_t*)alloc((size_t)BATCH * HID * 2);          // 256 KB
    bf16_t* hbufB  = (bf16_t*)alloc((size_t)BATCH * HID * 2);          // 256 KB
    bf16_t* Hdec   = (bf16_t*)alloc((size_t)TOUT * BATCH * HID * 2);   // 12.6 MB
    u32* flags     = (u32*)alloc((size_t)NGRP * NJB * 4);              // 512 B

    // per-launch state init (replay-safe)
    (void)hipMemsetAsync(hbufA, 0, (size_t)BATCH * HID * 2, stream);
    (void)hipMemsetAsync(flags, 0, (size_t)NGRP * NJB * 4, stream);

    // precompute
    cast_x_kernel<<<(BATCH * TIN * (FEAT / 4) + 255) / 256, 256, 0, stream>>>(x, Xbf);
    cast_wcat_kernel<<<(2048 * 160 + 255) / 256, 256, 0, stream>>>(enc_Wih, enc_Whh, Wenc);
    cast_wcat_kernel<<<(2048 * 160 + 255) / 256, 256, 0, stream>>>(dec_Wih, dec_Whh, Wdec1);
    cast_wlin_kernel<<<(FEAT * HID / 4 + 255) / 256, 256, 0, stream>>>(W_lin, Wlinb);
    build_wcomb_kernel<<<dim3(2048 / 64, HID / 64), 256, 0, stream>>>(dec_Wih, dec_Whh, W_lin, Wcomb);

    // all 216 recurrent steps in one persistent kernel (128 blocks x 256 thr)
    lstm_persist<<<NGRP * NJB, 256, 0, stream>>>(Xbf, Wenc, enc_b, Wdec1, Wcomb, dec_b,
                                                 hbufA, hbufB, Hdec, flags);

    // batched output projection (48 x 256 rows @ W_lin^T)
    final_proj_kernel<<<(TOUT * BATCH) / 32, 128, 0, stream>>>(Hdec, Wlinb, out);
}

// Round 15
// 1149.986 us; speedup vs baseline: 1.6314x; 1.2257x over previous
//
#include <hip/hip_runtime.h>
#include <hip/hip_bf16.h>

typedef __bf16 bf16_t;
typedef __bf16 bf16x8 __attribute__((ext_vector_type(8)));
typedef __bf16 bf16x4 __attribute__((ext_vector_type(4)));
typedef float  f32x4  __attribute__((ext_vector_type(4)));
typedef unsigned int u32;
typedef unsigned long long u64;

#define HID 512
#define BATCH 256
#define TIN 168
#define TOUT 48
#define FEAT 128
#define NSTEPS (TIN + TOUT)   // 216
#define NGRP 8                // batch groups
#define NJT 32                // blocks per group (j-tiles of 16)
#define GRPB 32               // batch rows per group

__device__ __forceinline__ float sigmoidf_(float x) {
    x = fminf(fmaxf(x, -30.f), 30.f);
    return 1.f / (1.f + __expf(-x));
}
__device__ __forceinline__ float tanhf_(float x) {
    x = fminf(fmaxf(x, -15.f), 15.f);
    float e = __expf(2.f * x);
    return (e - 1.f) / (e + 1.f);
}

// Coherent IC-through primitives (R4/R10-proven): RELAXED system-scope atomics
// compile to global_load/store ... sc0 sc1 — no cache-maintenance ops.
__device__ __forceinline__ bf16x8 ld_h8(const bf16_t* p) {
    union { u64 q[2]; bf16x8 v; } u;
    u.q[0] = __hip_atomic_load((const u64*)p,     __ATOMIC_RELAXED,
                               __HIP_MEMORY_SCOPE_SYSTEM);
    u.q[1] = __hip_atomic_load((const u64*)p + 1, __ATOMIC_RELAXED,
                               __HIP_MEMORY_SCOPE_SYSTEM);
    return u.v;
}
// one 8B store of 4 consecutive bf16 h-values
__device__ __forceinline__ void st_h4(bf16_t* p, float v0, float v1, float v2, float v3) {
    bf16_t b0 = (bf16_t)v0, b1 = (bf16_t)v1, b2 = (bf16_t)v2, b3 = (bf16_t)v3;
    unsigned short s0, s1, s2, s3;
    __builtin_memcpy(&s0, &b0, 2); __builtin_memcpy(&s1, &b1, 2);
    __builtin_memcpy(&s2, &b2, 2); __builtin_memcpy(&s3, &b3, 2);
    u64 w = (u64)s0 | ((u64)s1 << 16) | ((u64)s2 << 32) | ((u64)s3 << 48);
    __hip_atomic_store((u64*)p, w, __ATOMIC_RELAXED, __HIP_MEMORY_SCOPE_SYSTEM);
}

// ---------------------------------------------------------------------------
// Cast x (B,T,F) fp32 -> Xbf (T,B,F) bf16
__global__ __launch_bounds__(256)
void cast_x_kernel(const float* __restrict__ x, bf16_t* __restrict__ Xbf) {
    int q = blockIdx.x * 256 + threadIdx.x;
    if (q >= BATCH * TIN * (FEAT / 4)) return;
    int f4  = q & 31;
    int rem = q >> 5;
    int t = rem % TIN;
    int b = rem / TIN;
    float4 v = *(const float4*)&x[((size_t)b * TIN + t) * FEAT + f4 * 4];
    bf16x4 o = { (bf16_t)v.x, (bf16_t)v.y, (bf16_t)v.z, (bf16_t)v.w };
    *(bf16x4*)&Xbf[((size_t)t * BATCH + b) * FEAT + f4 * 4] = o;
}

// Build Wcat (2048 x 640) bf16 = [Wih | Whh]
__global__ __launch_bounds__(256)
void cast_wcat_kernel(const float* __restrict__ Wih, const float* __restrict__ Whh,
                      bf16_t* __restrict__ Wcat) {
    int q = blockIdx.x * 256 + threadIdx.x;
    int k4 = q % 160;
    int r  = q / 160;
    if (r >= 2048) return;
    int k = k4 * 4;
    float4 v;
    if (k < FEAT) v = *(const float4*)&Wih[(size_t)r * FEAT + k];
    else          v = *(const float4*)&Whh[(size_t)r * HID + (k - FEAT)];
    bf16x4 o = { (bf16_t)v.x, (bf16_t)v.y, (bf16_t)v.z, (bf16_t)v.w };
    *(bf16x4*)&Wcat[(size_t)r * 640 + k] = o;
}

// Cast W_lin (128 x 512) fp32 -> bf16
__global__ __launch_bounds__(256)
void cast_wlin_kernel(const float* __restrict__ W, bf16_t* __restrict__ Wb) {
    int q = blockIdx.x * 256 + threadIdx.x;
    if (q >= FEAT * HID / 4) return;
    float4 v = *(const float4*)&W[q * 4];
    bf16x4 o = { (bf16_t)v.x, (bf16_t)v.y, (bf16_t)v.z, (bf16_t)v.w };
    *(bf16x4*)&Wb[q * 4] = o;
}

// Wcomb (2048 x 512) = dec_Wih (2048x128) @ W_lin (128x512) + dec_Whh, bf16 out
__global__ __launch_bounds__(256)
void build_wcomb_kernel(const float* __restrict__ dWih, const float* __restrict__ dWhh,
                        const float* __restrict__ Wlin, bf16_t* __restrict__ Wcomb) {
    __shared__ float As[64][128];
    __shared__ float Bs[128][64];
    int r0 = blockIdx.x * 64, c0 = blockIdx.y * 64;
    int tid = threadIdx.x;
    for (int i = tid; i < 64 * 32; i += 256) {
        int rr = i >> 5, cc = (i & 31) << 2;
        *(float4*)&As[rr][cc] = *(const float4*)&dWih[(size_t)(r0 + rr) * 128 + cc];
    }
    for (int i = tid; i < 128 * 16; i += 256) {
        int kk = i >> 4, cc = (i & 15) << 2;
        *(float4*)&Bs[kk][cc] = *(const float4*)&Wlin[(size_t)kk * HID + c0 + cc];
    }
    __syncthreads();
    int tx = tid & 15, ty = tid >> 4;
    float acc[4][4] = {};
    for (int k = 0; k < 128; ++k) {
        float a[4], b[4];
        #pragma unroll
        for (int i = 0; i < 4; ++i) a[i] = As[ty * 4 + i][k];
        #pragma unroll
        for (int j = 0; j < 4; ++j) b[j] = Bs[k][tx * 4 + j];
        #pragma unroll
        for (int i = 0; i < 4; ++i)
            #pragma unroll
            for (int j = 0; j < 4; ++j) acc[i][j] += a[i] * b[j];
    }
    for (int i = 0; i < 4; ++i) {
        int r = r0 + ty * 4 + i;
        for (int j = 0; j < 4; ++j) {
            int cc = c0 + tx * 4 + j;
            Wcomb[(size_t)r * HID + cc] = (bf16_t)(acc[i][j] + dWhh[(size_t)r * HID + cc]);
        }
    }
}

// ---------------------------------------------------------------------------
// Persistent seq2seq LSTM — R10 base + early per-(block,bh) flags + x-prefetch.
// 256 blocks x 256 threads. Block -> (group g = bid&7, j-tile jt = bid>>3).
// Group owns 32 batch rows; block owns 16 hidden cols. Waves: bh = wave&1
// (batch half), gp = wave>>1 (K half). Weights pinned in regs; c register-
// resident. Swapped mfma(W, xh): lane owns batch row b0+l15, 4 consecutive
// hidden cols -> ONE 8B h store per lane.
// Flags: per (block,bh) = 64/group. gp0-bh wave sets ITS OWN flag right
// after ITS OWN drain (before the trailing barrier) — consumer wave (bh)
// only reads h rows of its own batch half, so cross-bh coupling is slack.
// Poll: single wave (wave 0), 64 lanes x 1 flag; barrier releases block.

__device__ __forceinline__ void group_wait(const u32* flags, int g, int tid,
                                           u32 epoch) {
    if (tid < 64) {   // wave 0 polls all 64 (jt,bh) flags
        const u32* fp = &flags[g * 64 + tid];
        while (__hip_atomic_load(fp, __ATOMIC_RELAXED,
                                 __HIP_MEMORY_SCOPE_SYSTEM) < epoch)
            __builtin_amdgcn_s_sleep(1);
    }
    __syncthreads();
}

// gp1 -> Ex; barrier; gp0: merge, cell, packed store, drain, OWN flag; barrier.
__device__ __forceinline__ void cell_finish(
    f32x4 (&acc)[4], float (&cacc)[4], f32x4 (*Ex)[2][64],
    u32* flags, int g, int jt, int gp, int bh, int lane, int brow, int jq0,
    u32 epoch_next, bf16_t* __restrict__ hnext)
{
    if (gp == 1) {
        #pragma unroll
        for (int q = 0; q < 4; ++q)
            Ex[q][bh][lane] = acc[q];
    }
    __syncthreads();
    if (gp == 0) {
        #pragma unroll
        for (int q = 0; q < 4; ++q)
            acc[q] += Ex[q][bh][lane];
        float hv[4];
        #pragma unroll
        for (int r = 0; r < 4; ++r) {
            float cn = sigmoidf_(acc[1][r]) * cacc[r] + sigmoidf_(acc[0][r]) * tanhf_(acc[2][r]);
            cacc[r] = cn;
            hv[r] = sigmoidf_(acc[3][r]) * tanhf_(cn);
        }
        st_h4(hnext + (size_t)brow * HID + jq0, hv[0], hv[1], hv[2], hv[3]);
        asm volatile("s_waitcnt vmcnt(0)" ::: "memory");   // THIS wave's h acked
        if (lane == 0)
            __hip_atomic_store(&flags[g * 64 + jt * 2 + bh], epoch_next,
                               __ATOMIC_RELAXED, __HIP_MEMORY_SCOPE_SYSTEM);
    }
    __syncthreads();   // Ex-reuse safety (unchanged from R10)
}

__global__ __launch_bounds__(256, 1)
void lstm_persist(const bf16_t* __restrict__ Xbf,
                  const bf16_t* __restrict__ Wenc, const float* __restrict__ enc_b,
                  const bf16_t* __restrict__ Wdec1, const bf16_t* __restrict__ Wcomb,
                  const float* __restrict__ dec_b,
                  bf16_t* __restrict__ hbufA, bf16_t* __restrict__ hbufB,
                  bf16_t* __restrict__ Hdec, u32* __restrict__ flags)
{
    __shared__ f32x4 Ex[4][2][64];     // 8 KB exchange
    const int bid = blockIdx.x;
    const int g   = bid & (NGRP - 1);
    const int jt  = bid >> 3;
    const int j0  = jt * 16;
    const int tid = threadIdx.x;
    const int wave = tid >> 6, lane = tid & 63;
    const int l15 = lane & 15, l4 = lane >> 4;
    const int bh = wave & 1, gp = wave >> 1;
    const int b0 = g * GRPB + bh * 16;
    const int arow = b0 + l15;          // batch row this lane owns (B-operand)
    const int jcol = j0 + l15;          // W row for fragment load (A-operand)
    const int jq0  = j0 + l4 * 4;       // first of this lane's 4 hidden cols

    f32x4 biasE4[4], biasD4[4];
    #pragma unroll
    for (int q = 0; q < 4; ++q) {
        biasE4[q] = *(const f32x4*)&enc_b[q * HID + jq0];
        biasD4[q] = *(const f32x4*)&dec_b[q * HID + jq0];
    }
    float cacc[4] = {0.f, 0.f, 0.f, 0.f};

    bf16x8 Breg[40];
    const int kc0 = gp * 320;    // K-half base for K=640 phases

    // ---- encoder weight fragments (K=640), pinned
    #pragma unroll
    for (int q = 0; q < 4; ++q)
        #pragma unroll
        for (int i = 0; i < 10; ++i)
            Breg[q * 10 + i] = *(const bf16x8*)(
                Wenc + (size_t)(q * HID + jcol) * 640 + kc0 + i * 32 + l4 * 8);
    #pragma unroll
    for (int n = 0; n < 40; ++n) asm volatile("" : "+v"(Breg[n]));

    // ================= encoder: t = 0..167 =================
    for (int t = 0; t < TIN; ++t) {
        const bf16_t* hb = (t & 1) ? hbufB : hbufA;
        bf16_t* hn       = (t & 1) ? hbufA : hbufB;
        bf16x8 a[10];
        // x prefetch (flag-independent) BEFORE the wait
        const bf16_t* xb = Xbf + ((size_t)t * BATCH + arow) * FEAT + l4 * 8;
        if (gp == 0) {
            #pragma unroll
            for (int i = 0; i < 4; ++i) a[i] = *(const bf16x8*)(xb + i * 32);
        }
        if (t > 0) group_wait(flags, g, tid, (u32)t);
        const bf16_t* hbp = hb + (size_t)arow * HID + l4 * 8;
        if (gp == 0) {
            #pragma unroll
            for (int i = 4; i < 10; ++i) a[i] = ld_h8(hbp + (i * 32 - FEAT));
        } else {
            #pragma unroll
            for (int i = 0; i < 10; ++i) a[i] = ld_h8(hbp + (320 - FEAT) + i * 32);
        }
        f32x4 acc[4];
        #pragma unroll
        for (int q = 0; q < 4; ++q)
            acc[q] = (gp == 0) ? biasE4[q] : (f32x4){0.f, 0.f, 0.f, 0.f};
        #pragma unroll
        for (int i = 0; i < 10; ++i)
            #pragma unroll
            for (int q = 0; q < 4; ++q)
                acc[q] = __builtin_amdgcn_mfma_f32_16x16x32_bf16(Breg[q * 10 + i], a[i], acc[q], 0, 0, 0);
        cell_finish(acc, cacc, Ex, flags, g, jt, gp, bh, lane, arow, jq0,
                    (u32)(t + 1), hn);
    }

    // ---- decoder step 0 weights (Wdec1, K=640)
    #pragma unroll
    for (int q = 0; q < 4; ++q)
        #pragma unroll
        for (int i = 0; i < 10; ++i)
            Breg[q * 10 + i] = *(const bf16x8*)(
                Wdec1 + (size_t)(q * HID + jcol) * 640 + kc0 + i * 32 + l4 * 8);
    #pragma unroll
    for (int n = 0; n < 40; ++n) asm volatile("" : "+v"(Breg[n]));

    // ================= decoder step 0: t = 168 =================
    {
        const int t = TIN;
        bf16x8 a[10];
        const bf16_t* xb = Xbf + ((size_t)(TIN - 1) * BATCH + arow) * FEAT + l4 * 8;
        if (gp == 0) {
            #pragma unroll
            for (int i = 0; i < 4; ++i) a[i] = *(const bf16x8*)(xb + i * 32);
        }
        group_wait(flags, g, tid, (u32)t);
        // h_168 lives in hbufA (written at t=167)
        const bf16_t* hbp = hbufA + (size_t)arow * HID + l4 * 8;
        if (gp == 0) {
            #pragma unroll
            for (int i = 4; i < 10; ++i) a[i] = ld_h8(hbp + (i * 32 - FEAT));
        } else {
            #pragma unroll
            for (int i = 0; i < 10; ++i) a[i] = ld_h8(hbp + (320 - FEAT) + i * 32);
        }
        f32x4 acc[4];
        #pragma unroll
        for (int q = 0; q < 4; ++q)
            acc[q] = (gp == 0) ? biasD4[q] : (f32x4){0.f, 0.f, 0.f, 0.f};
        #pragma unroll
        for (int i = 0; i < 10; ++i)
            #pragma unroll
            for (int q = 0; q < 4; ++q)
                acc[q] = __builtin_amdgcn_mfma_f32_16x16x32_bf16(Breg[q * 10 + i], a[i], acc[q], 0, 0, 0);
        cell_finish(acc, cacc, Ex, flags, g, jt, gp, bh, lane, arow, jq0,
                    (u32)(t + 1), Hdec);
    }

    // ---- folded decoder weights (Wcomb, K=512)
    const int kd0 = gp * 256;
    #pragma unroll
    for (int q = 0; q < 4; ++q)
        #pragma unroll
        for (int i = 0; i < 8; ++i)
            Breg[q * 8 + i] = *(const bf16x8*)(
                Wcomb + (size_t)(q * HID + jcol) * HID + kd0 + i * 32 + l4 * 8);
    #pragma unroll
    for (int n = 0; n < 32; ++n) asm volatile("" : "+v"(Breg[n]));

    // ================= decoder: t = 169..215 =================
    for (int t = TIN + 1; t < NSTEPS; ++t) {
        group_wait(flags, g, tid, (u32)t);
        const bf16_t* hprev = Hdec + (size_t)(t - 1 - TIN) * BATCH * HID
                                   + (size_t)arow * HID + l4 * 8;
        bf16x8 a[8];
        #pragma unroll
        for (int i = 0; i < 8; ++i)
            a[i] = ld_h8(hprev + kd0 + i * 32);
        f32x4 acc[4];
        #pragma unroll
        for (int q = 0; q < 4; ++q)
            acc[q] = (gp == 0) ? biasD4[q] : (f32x4){0.f, 0.f, 0.f, 0.f};
        #pragma unroll
        for (int i = 0; i < 8; ++i)
            #pragma unroll
            for (int q = 0; q < 4; ++q)
                acc[q] = __builtin_amdgcn_mfma_f32_16x16x32_bf16(Breg[q * 8 + i], a[i], acc[q], 0, 0, 0);
        cell_finish(acc, cacc, Ex, flags, g, jt, gp, bh, lane, arow, jq0,
                    (u32)(t + 1), Hdec + (size_t)(t - TIN) * BATCH * HID);
    }
}

// ---------------------------------------------------------------------------
// Final projection: out[b,t,f] = sum_j Hdec[t][b][j] * Wlin[f][j]
__global__ __launch_bounds__(128)
void final_proj_kernel(const bf16_t* __restrict__ Hdec, const bf16_t* __restrict__ Wlin,
                       float* __restrict__ out) {
    int tid = threadIdx.x;
    int wv = tid >> 6, lane = tid & 63;
    int l15 = lane & 15, l4 = lane >> 4;
    int row0 = blockIdx.x * 32 + wv * 16;
    const bf16_t* arow = Hdec + (size_t)(row0 + l15) * HID;
    f32x4 acc[8];
    #pragma unroll
    for (int n = 0; n < 8; ++n) acc[n] = (f32x4){0.f, 0.f, 0.f, 0.f};
    #pragma unroll 4
    for (int kc = 0; kc < HID; kc += 32) {
        bf16x8 af = *(const bf16x8*)(arow + kc + l4 * 8);
        #pragma unroll
        for (int n = 0; n < 8; ++n) {
            bf16x8 bfr = *(const bf16x8*)(Wlin + (size_t)(n * 16 + l15) * HID + kc + l4 * 8);
            acc[n] = __builtin_amdgcn_mfma_f32_16x16x32_bf16(af, bfr, acc[n], 0, 0, 0);
        }
    }
    #pragma unroll
    for (int n = 0; n < 8; ++n) {
        int f = n * 16 + l15;
        #pragma unroll
        for (int r = 0; r < 4; ++r) {
            int row = row0 + l4 * 4 + r;
            int t = row >> 8;
            int b = row & 255;
            out[(size_t)b * (TOUT * FEAT) + (size_t)t * FEAT + f] = acc[n][r];
        }
    }
}

// ---------------------------------------------------------------------------
extern "C" void kernel_launch(void* const* d_in, const int* in_sizes, int n_in,
                              void* d_out, int out_size, void* d_ws, size_t ws_size,
                              hipStream_t stream) {
    const float* x       = (const float*)d_in[0];
    const float* enc_Wih = (const float*)d_in[1];
    const float* enc_Whh = (const float*)d_in[2];
    const float* enc_b   = (const float*)d_in[3];
    const float* dec_Wih = (const float*)d_in[4];
    const float* dec_Whh = (const float*)d_in[5];
    const float* dec_b   = (const float*)d_in[6];
    const float* W_lin   = (const float*)d_in[7];
    float* out = (float*)d_out;

    char* p = (char*)d_ws;
    auto alloc = [&](size_t bytes) -> void* {
        void* r = (void*)p;
        p += (bytes + 255) & ~(size_t)255;
        return r;
    };
    bf16_t* Xbf    = (bf16_t*)alloc((size_t)TIN * BATCH * FEAT * 2);   // 11 MB
    bf16_t* Wenc   = (bf16_t*)alloc((size_t)2048 * 640 * 2);           // 2.6 MB
    bf16_t* Wdec1  = (bf16_t*)alloc((size_t)2048 * 640 * 2);           // 2.6 MB
    bf16_t* Wcomb  = (bf16_t*)alloc((size_t)2048 * HID * 2);           // 2.1 MB
    bf16_t* Wlinb  = (bf16_t*)alloc((size_t)FEAT * HID * 2);           // 128 KB
    bf16_t* hbufA  = (bf16_t*)alloc((size_t)BATCH * HID * 2);          // 256 KB
    bf16_t* hbufB  = (bf16_t*)alloc((size_t)BATCH * HID * 2);          // 256 KB
    bf16_t* Hdec   = (bf16_t*)alloc((size_t)TOUT * BATCH * HID * 2);   // 12.6 MB
    u32* flags     = (u32*)alloc((size_t)NGRP * 64 * 4);               // 2 KB

    // per-launch state init (replay-safe)
    (void)hipMemsetAsync(hbufA, 0, (size_t)BATCH * HID * 2, stream);
    (void)hipMemsetAsync(flags, 0, (size_t)NGRP * 64 * 4, stream);

    // precompute
    cast_x_kernel<<<(BATCH * TIN * (FEAT / 4) + 255) / 256, 256, 0, stream>>>(x, Xbf);
    cast_wcat_kernel<<<(2048 * 160 + 255) / 256, 256, 0, stream>>>(enc_Wih, enc_Whh, Wenc);
    cast_wcat_kernel<<<(2048 * 160 + 255) / 256, 256, 0, stream>>>(dec_Wih, dec_Whh, Wdec1);
    cast_wlin_kernel<<<(FEAT * HID / 4 + 255) / 256, 256, 0, stream>>>(W_lin, Wlinb);
    build_wcomb_kernel<<<dim3(2048 / 64, HID / 64), 256, 0, stream>>>(dec_Wih, dec_Whh, W_lin, Wcomb);

    // all 216 recurrent steps in one persistent kernel
    lstm_persist<<<NGRP * NJT, 256, 0, stream>>>(Xbf, Wenc, enc_b, Wdec1, Wcomb, dec_b,
                                                 hbufA, hbufB, Hdec, flags);

    // batched output projection (48 x 256 rows @ W_lin^T)
    final_proj_kernel<<<(TOUT * BATCH) / 32, 128, 0, stream>>>(Hdec, Wlinb, out);
}

// Round 16
// 1003.823 us; speedup vs baseline: 1.8690x; 1.1456x over previous
//
#include <hip/hip_runtime.h>
#include <hip/hip_bf16.h>

typedef __bf16 bf16_t;
typedef __bf16 bf16x8 __attribute__((ext_vector_type(8)));
typedef __bf16 bf16x4 __attribute__((ext_vector_type(4)));
typedef float  f32x4  __attribute__((ext_vector_type(4)));
typedef unsigned int u32;
typedef unsigned long long u64;

#define HID 512
#define BATCH 256
#define TIN 168
#define TOUT 48
#define FEAT 128
#define NSTEPS (TIN + TOUT)   // 216
#define NGRP 8                // batch groups
#define NJT 32                // blocks per group (j-tiles of 16)
#define GRPB 32               // batch rows per group

__device__ __forceinline__ float sigmoidf_(float x) {
    x = fminf(fmaxf(x, -30.f), 30.f);
    return 1.f / (1.f + __expf(-x));
}
__device__ __forceinline__ float tanhf_(float x) {
    x = fminf(fmaxf(x, -15.f), 15.f);
    float e = __expf(2.f * x);
    return (e - 1.f) / (e + 1.f);
}

// Coherent IC-through primitives (R4/R10-proven): RELAXED system-scope atomics
// compile to global_load/store ... sc0 sc1 — no cache-maintenance ops.
__device__ __forceinline__ bf16x8 ld_h8(const bf16_t* p) {
    union { u64 q[2]; bf16x8 v; } u;
    u.q[0] = __hip_atomic_load((const u64*)p,     __ATOMIC_RELAXED,
                               __HIP_MEMORY_SCOPE_SYSTEM);
    u.q[1] = __hip_atomic_load((const u64*)p + 1, __ATOMIC_RELAXED,
                               __HIP_MEMORY_SCOPE_SYSTEM);
    return u.v;
}
// one 8B store of 4 consecutive bf16 h-values (R5-proven u64 atomic store)
__device__ __forceinline__ void st_h4(bf16_t* p, float v0, float v1, float v2, float v3) {
    bf16_t b0 = (bf16_t)v0, b1 = (bf16_t)v1, b2 = (bf16_t)v2, b3 = (bf16_t)v3;
    unsigned short s0, s1, s2, s3;
    __builtin_memcpy(&s0, &b0, 2); __builtin_memcpy(&s1, &b1, 2);
    __builtin_memcpy(&s2, &b2, 2); __builtin_memcpy(&s3, &b3, 2);
    u64 w = (u64)s0 | ((u64)s1 << 16) | ((u64)s2 << 32) | ((u64)s3 << 48);
    __hip_atomic_store((u64*)p, w, __ATOMIC_RELAXED, __HIP_MEMORY_SCOPE_SYSTEM);
}

// ---------------------------------------------------------------------------
// Cast x (B,T,F) fp32 -> Xbf (T,B,F) bf16
__global__ __launch_bounds__(256)
void cast_x_kernel(const float* __restrict__ x, bf16_t* __restrict__ Xbf) {
    int q = blockIdx.x * 256 + threadIdx.x;
    if (q >= BATCH * TIN * (FEAT / 4)) return;
    int f4  = q & 31;
    int rem = q >> 5;
    int t = rem % TIN;
    int b = rem / TIN;
    float4 v = *(const float4*)&x[((size_t)b * TIN + t) * FEAT + f4 * 4];
    bf16x4 o = { (bf16_t)v.x, (bf16_t)v.y, (bf16_t)v.z, (bf16_t)v.w };
    *(bf16x4*)&Xbf[((size_t)t * BATCH + b) * FEAT + f4 * 4] = o;
}

// Build Wcat (2048 x 640) bf16 = [Wih | Whh]
__global__ __launch_bounds__(256)
void cast_wcat_kernel(const float* __restrict__ Wih, const float* __restrict__ Whh,
                      bf16_t* __restrict__ Wcat) {
    int q = blockIdx.x * 256 + threadIdx.x;
    int k4 = q % 160;
    int r  = q / 160;
    if (r >= 2048) return;
    int k = k4 * 4;
    float4 v;
    if (k < FEAT) v = *(const float4*)&Wih[(size_t)r * FEAT + k];
    else          v = *(const float4*)&Whh[(size_t)r * HID + (k - FEAT)];
    bf16x4 o = { (bf16_t)v.x, (bf16_t)v.y, (bf16_t)v.z, (bf16_t)v.w };
    *(bf16x4*)&Wcat[(size_t)r * 640 + k] = o;
}

// Cast W_lin (128 x 512) fp32 -> bf16
__global__ __launch_bounds__(256)
void cast_wlin_kernel(const float* __restrict__ W, bf16_t* __restrict__ Wb) {
    int q = blockIdx.x * 256 + threadIdx.x;
    if (q >= FEAT * HID / 4) return;
    float4 v = *(const float4*)&W[q * 4];
    bf16x4 o = { (bf16_t)v.x, (bf16_t)v.y, (bf16_t)v.z, (bf16_t)v.w };
    *(bf16x4*)&Wb[q * 4] = o;
}

// Wcomb (2048 x 512) = dec_Wih (2048x128) @ W_lin (128x512) + dec_Whh, bf16 out
__global__ __launch_bounds__(256)
void build_wcomb_kernel(const float* __restrict__ dWih, const float* __restrict__ dWhh,
                        const float* __restrict__ Wlin, bf16_t* __restrict__ Wcomb) {
    __shared__ float As[64][128];
    __shared__ float Bs[128][64];
    int r0 = blockIdx.x * 64, c0 = blockIdx.y * 64;
    int tid = threadIdx.x;
    for (int i = tid; i < 64 * 32; i += 256) {
        int rr = i >> 5, cc = (i & 31) << 2;
        *(float4*)&As[rr][cc] = *(const float4*)&dWih[(size_t)(r0 + rr) * 128 + cc];
    }
    for (int i = tid; i < 128 * 16; i += 256) {
        int kk = i >> 4, cc = (i & 15) << 2;
        *(float4*)&Bs[kk][cc] = *(const float4*)&Wlin[(size_t)kk * HID + c0 + cc];
    }
    __syncthreads();
    int tx = tid & 15, ty = tid >> 4;
    float acc[4][4] = {};
    for (int k = 0; k < 128; ++k) {
        float a[4], b[4];
        #pragma unroll
        for (int i = 0; i < 4; ++i) a[i] = As[ty * 4 + i][k];
        #pragma unroll
        for (int j = 0; j < 4; ++j) b[j] = Bs[k][tx * 4 + j];
        #pragma unroll
        for (int i = 0; i < 4; ++i)
            #pragma unroll
            for (int j = 0; j < 4; ++j) acc[i][j] += a[i] * b[j];
    }
    for (int i = 0; i < 4; ++i) {
        int r = r0 + ty * 4 + i;
        for (int j = 0; j < 4; ++j) {
            int cc = c0 + tx * 4 + j;
            Wcomb[(size_t)r * HID + cc] = (bf16_t)(acc[i][j] + dWhh[(size_t)r * HID + cc]);
        }
    }
}

// ---------------------------------------------------------------------------
// Persistent seq2seq LSTM — R4 skeleton, operand-swapped MFMA (R10 champion).
// 256 blocks x 256 threads. Block -> (group g = bid&7, j-tile jt = bid>>3).
// Group owns 32 batch rows; block owns 16 hidden cols. Waves: bh = wave&1
// (batch half), gp = wave>>1 (K half). Weights pinned in regs; c register-
// resident. mfma(W_frag, xh_frag, acc): D col (lane&15) = batch row,
// D row (l4*4+r) = hidden col -> each lane holds 4 CONSECUTIVE hidden cols
// for one batch row -> h write-back is ONE 8B store per lane.

// wait until all 32 blocks of group g have flag >= epoch (R4-proven)
__device__ __forceinline__ void group_wait(const u32* flags, int g, int tid,
                                           unsigned int epoch) {
    if (tid < NJT) {
        while (__hip_atomic_load(&flags[g * NJT + tid], __ATOMIC_RELAXED,
                                 __HIP_MEMORY_SCOPE_SYSTEM) < epoch)
            __builtin_amdgcn_s_sleep(1);
    }
    __syncthreads();
}

__device__ __forceinline__ void group_arrive(u32* flags, int g, int jt, int tid,
                                             unsigned int epoch) {
    if (tid == 0)
        __hip_atomic_store(&flags[g * NJT + jt], epoch, __ATOMIC_RELAXED,
                           __HIP_MEMORY_SCOPE_SYSTEM);
}

// gp1 -> Ex; barrier; gp0: merge K-halves, cell update, packed 8B h store,
// drain; barrier. (two-barrier R4 structure)
__device__ __forceinline__ void cell_finish(
    f32x4 (&acc)[4], float (&cacc)[4], f32x4 (*Ex)[2][64],
    int gp, int bh, int lane, int l15, int l4, int brow, int jq0,
    bf16_t* __restrict__ hnext)
{
    if (gp == 1) {
        #pragma unroll
        for (int q = 0; q < 4; ++q)
            Ex[q][bh][lane] = acc[q];
    }
    __syncthreads();
    if (gp == 0) {
        #pragma unroll
        for (int q = 0; q < 4; ++q)
            acc[q] += Ex[q][bh][lane];
        float hv[4];
        #pragma unroll
        for (int r = 0; r < 4; ++r) {
            float cn = sigmoidf_(acc[1][r]) * cacc[r] + sigmoidf_(acc[0][r]) * tanhf_(acc[2][r]);
            cacc[r] = cn;
            hv[r] = sigmoidf_(acc[3][r]) * tanhf_(cn);
        }
        st_h4(hnext + (size_t)brow * HID + jq0, hv[0], hv[1], hv[2], hv[3]);
        asm volatile("s_waitcnt vmcnt(0)" ::: "memory");   // h acked at IC
    }
    __syncthreads();
}

__global__ __launch_bounds__(256, 1)
void lstm_persist(const bf16_t* __restrict__ Xbf,
                  const bf16_t* __restrict__ Wenc, const float* __restrict__ enc_b,
                  const bf16_t* __restrict__ Wdec1, const bf16_t* __restrict__ Wcomb,
                  const float* __restrict__ dec_b,
                  bf16_t* __restrict__ hbufA, bf16_t* __restrict__ hbufB,
                  bf16_t* __restrict__ Hdec, u32* __restrict__ flags)
{
    __shared__ f32x4 Ex[4][2][64];     // 8 KB exchange
    const int bid = blockIdx.x;
    const int g   = bid & (NGRP - 1);
    const int jt  = bid >> 3;
    const int j0  = jt * 16;
    const int tid = threadIdx.x;
    const int wave = tid >> 6, lane = tid & 63;
    const int l15 = lane & 15, l4 = lane >> 4;
    const int bh = wave & 1, gp = wave >> 1;
    const int b0 = g * GRPB + bh * 16;
    const int arow = b0 + l15;          // batch row this lane loads/owns (B-op)
    const int jcol = j0 + l15;          // W row for fragment load (A-op)
    const int jq0  = j0 + l4 * 4;       // first of this lane's 4 hidden cols

    // bias as float4 over the lane's 4 consecutive hidden cols, per gate
    f32x4 biasE4[4], biasD4[4];
    #pragma unroll
    for (int q = 0; q < 4; ++q) {
        biasE4[q] = *(const f32x4*)&enc_b[q * HID + jq0];
        biasD4[q] = *(const f32x4*)&dec_b[q * HID + jq0];
    }
    float cacc[4] = {0.f, 0.f, 0.f, 0.f};

    bf16x8 Breg[40];
    const int kc0 = gp * 320;    // K-half base for K=640 phases

    // ---- encoder weight fragments (K=640), pinned
    #pragma unroll
    for (int q = 0; q < 4; ++q)
        #pragma unroll
        for (int i = 0; i < 10; ++i)
            Breg[q * 10 + i] = *(const bf16x8*)(
                Wenc + (size_t)(q * HID + jcol) * 640 + kc0 + i * 32 + l4 * 8);
    #pragma unroll
    for (int n = 0; n < 40; ++n) asm volatile("" : "+v"(Breg[n]));

    // ================= encoder: t = 0..167 =================
    for (int t = 0; t < TIN; ++t) {
        if (t > 0) group_wait(flags, g, tid, (unsigned)t);
        const bf16_t* hb = (t & 1) ? hbufB : hbufA;
        bf16_t* hn       = (t & 1) ? hbufA : hbufB;
        const bf16_t* xb  = Xbf + ((size_t)t * BATCH + arow) * FEAT + l4 * 8;
        const bf16_t* hbp = hb + (size_t)arow * HID + l4 * 8;
        bf16x8 a[10];
        if (gp == 0) {
            #pragma unroll
            for (int i = 0; i < 4; ++i)  a[i] = *(const bf16x8*)(xb + i * 32);
            #pragma unroll
            for (int i = 4; i < 10; ++i) a[i] = ld_h8(hbp + (i * 32 - FEAT));
        } else {
            #pragma unroll
            for (int i = 0; i < 10; ++i) a[i] = ld_h8(hbp + (320 - FEAT) + i * 32);
        }
        f32x4 acc[4];
        #pragma unroll
        for (int q = 0; q < 4; ++q)
            acc[q] = (gp == 0) ? biasE4[q] : (f32x4){0.f, 0.f, 0.f, 0.f};
        #pragma unroll
        for (int i = 0; i < 10; ++i)
            #pragma unroll
            for (int q = 0; q < 4; ++q)
                acc[q] = __builtin_amdgcn_mfma_f32_16x16x32_bf16(Breg[q * 10 + i], a[i], acc[q], 0, 0, 0);
        cell_finish(acc, cacc, Ex, gp, bh, lane, l15, l4, arow, jq0, hn);
        group_arrive(flags, g, jt, tid, (unsigned)(t + 1));
    }

    // ---- decoder step 0 weights (Wdec1, K=640)
    #pragma unroll
    for (int q = 0; q < 4; ++q)
        #pragma unroll
        for (int i = 0; i < 10; ++i)
            Breg[q * 10 + i] = *(const bf16x8*)(
                Wdec1 + (size_t)(q * HID + jcol) * 640 + kc0 + i * 32 + l4 * 8);
    #pragma unroll
    for (int n = 0; n < 40; ++n) asm volatile("" : "+v"(Breg[n]));

    // ================= decoder step 0: t = 168 =================
    {
        const int t = TIN;
        group_wait(flags, g, tid, (unsigned)t);
        // h_168 lives in hbufA (written at t=167)
        const bf16_t* xb  = Xbf + ((size_t)(TIN - 1) * BATCH + arow) * FEAT + l4 * 8;
        const bf16_t* hbp = hbufA + (size_t)arow * HID + l4 * 8;
        bf16x8 a[10];
        if (gp == 0) {
            #pragma unroll
            for (int i = 0; i < 4; ++i)  a[i] = *(const bf16x8*)(xb + i * 32);
            #pragma unroll
            for (int i = 4; i < 10; ++i) a[i] = ld_h8(hbp + (i * 32 - FEAT));
        } else {
            #pragma unroll
            for (int i = 0; i < 10; ++i) a[i] = ld_h8(hbp + (320 - FEAT) + i * 32);
        }
        f32x4 acc[4];
        #pragma unroll
        for (int q = 0; q < 4; ++q)
            acc[q] = (gp == 0) ? biasD4[q] : (f32x4){0.f, 0.f, 0.f, 0.f};
        #pragma unroll
        for (int i = 0; i < 10; ++i)
            #pragma unroll
            for (int q = 0; q < 4; ++q)
                acc[q] = __builtin_amdgcn_mfma_f32_16x16x32_bf16(Breg[q * 10 + i], a[i], acc[q], 0, 0, 0);
        cell_finish(acc, cacc, Ex, gp, bh, lane, l15, l4, arow, jq0, Hdec);
        group_arrive(flags, g, jt, tid, (unsigned)(t + 1));
    }

    // ---- folded decoder weights (Wcomb, K=512)
    const int kd0 = gp * 256;
    #pragma unroll
    for (int q = 0; q < 4; ++q)
        #pragma unroll
        for (int i = 0; i < 8; ++i)
            Breg[q * 8 + i] = *(const bf16x8*)(
                Wcomb + (size_t)(q * HID + jcol) * HID + kd0 + i * 32 + l4 * 8);
    #pragma unroll
    for (int n = 0; n < 32; ++n) asm volatile("" : "+v"(Breg[n]));

    // ================= decoder: t = 169..215 =================
    for (int t = TIN + 1; t < NSTEPS; ++t) {
        group_wait(flags, g, tid, (unsigned)t);
        const bf16_t* hprev = Hdec + (size_t)(t - 1 - TIN) * BATCH * HID
                                   + (size_t)arow * HID + l4 * 8;
        bf16x8 a[8];
        #pragma unroll
        for (int i = 0; i < 8; ++i)
            a[i] = ld_h8(hprev + kd0 + i * 32);
        f32x4 acc[4];
        #pragma unroll
        for (int q = 0; q < 4; ++q)
            acc[q] = (gp == 0) ? biasD4[q] : (f32x4){0.f, 0.f, 0.f, 0.f};
        #pragma unroll
        for (int i = 0; i < 8; ++i)
            #pragma unroll
            for (int q = 0; q < 4; ++q)
                acc[q] = __builtin_amdgcn_mfma_f32_16x16x32_bf16(Breg[q * 8 + i], a[i], acc[q], 0, 0, 0);
        cell_finish(acc, cacc, Ex, gp, bh, lane, l15, l4, arow, jq0,
                    Hdec + (size_t)(t - TIN) * BATCH * HID);
        group_arrive(flags, g, jt, tid, (unsigned)(t + 1));
    }
}

// ---------------------------------------------------------------------------
// Final projection: out[b,t,f] = sum_j Hdec[t][b][j] * Wlin[f][j]
__global__ __launch_bounds__(128)
void final_proj_kernel(const bf16_t* __restrict__ Hdec, const bf16_t* __restrict__ Wlin,
                       float* __restrict__ out) {
    int tid = threadIdx.x;
    int wv = tid >> 6, lane = tid & 63;
    int l15 = lane & 15, l4 = lane >> 4;
    int row0 = blockIdx.x * 32 + wv * 16;
    const bf16_t* arow = Hdec + (size_t)(row0 + l15) * HID;
    f32x4 acc[8];
    #pragma unroll
    for (int n = 0; n < 8; ++n) acc[n] = (f32x4){0.f, 0.f, 0.f, 0.f};
    #pragma unroll 4
    for (int kc = 0; kc < HID; kc += 32) {
        bf16x8 af = *(const bf16x8*)(arow + kc + l4 * 8);
        #pragma unroll
        for (int n = 0; n < 8; ++n) {
            bf16x8 bfr = *(const bf16x8*)(Wlin + (size_t)(n * 16 + l15) * HID + kc + l4 * 8);
            acc[n] = __builtin_amdgcn_mfma_f32_16x16x32_bf16(af, bfr, acc[n], 0, 0, 0);
        }
    }
    #pragma unroll
    for (int n = 0; n < 8; ++n) {
        int f = n * 16 + l15;
        #pragma unroll
        for (int r = 0; r < 4; ++r) {
            int row = row0 + l4 * 4 + r;
            int t = row >> 8;
            int b = row & 255;
            out[(size_t)b * (TOUT * FEAT) + (size_t)t * FEAT + f] = acc[n][r];
        }
    }
}

// ---------------------------------------------------------------------------
extern "C" void kernel_launch(void* const* d_in, const int* in_sizes, int n_in,
                              void* d_out, int out_size, void* d_ws, size_t ws_size,
                              hipStream_t stream) {
    const float* x       = (const float*)d_in[0];
    const float* enc_Wih = (const float*)d_in[1];
    const float* enc_Whh = (const float*)d_in[2];
    const float* enc_b   = (const float*)d_in[3];
    const float* dec_Wih = (const float*)d_in[4];
    const float* dec_Whh = (const float*)d_in[5];
    const float* dec_b   = (const float*)d_in[6];
    const float* W_lin   = (const float*)d_in[7];
    float* out = (float*)d_out;

    char* p = (char*)d_ws;
    auto alloc = [&](size_t bytes) -> void* {
        void* r = (void*)p;
        p += (bytes + 255) & ~(size_t)255;
        return r;
    };
    bf16_t* Xbf    = (bf16_t*)alloc((size_t)TIN * BATCH * FEAT * 2);   // 11 MB
    bf16_t* Wenc   = (bf16_t*)alloc((size_t)2048 * 640 * 2);           // 2.6 MB
    bf16_t* Wdec1  = (bf16_t*)alloc((size_t)2048 * 640 * 2);           // 2.6 MB
    bf16_t* Wcomb  = (bf16_t*)alloc((size_t)2048 * HID * 2);           // 2.1 MB
    bf16_t* Wlinb  = (bf16_t*)alloc((size_t)FEAT * HID * 2);           // 128 KB
    bf16_t* hbufA  = (bf16_t*)alloc((size_t)BATCH * HID * 2);          // 256 KB
    bf16_t* hbufB  = (bf16_t*)alloc((size_t)BATCH * HID * 2);          // 256 KB
    bf16_t* Hdec   = (bf16_t*)alloc((size_t)TOUT * BATCH * HID * 2);   // 12.6 MB
    u32* flags     = (u32*)alloc((size_t)NGRP * NJT * 4);              // 1 KB

    // per-launch state init (replay-safe)
    (void)hipMemsetAsync(hbufA, 0, (size_t)BATCH * HID * 2, stream);
    (void)hipMemsetAsync(flags, 0, (size_t)NGRP * NJT * 4, stream);

    // precompute
    cast_x_kernel<<<(BATCH * TIN * (FEAT / 4) + 255) / 256, 256, 0, stream>>>(x, Xbf);
    cast_wcat_kernel<<<(2048 * 160 + 255) / 256, 256, 0, stream>>>(enc_Wih, enc_Whh, Wenc);
    cast_wcat_kernel<<<(2048 * 160 + 255) / 256, 256, 0, stream>>>(dec_Wih, dec_Whh, Wdec1);
    cast_wlin_kernel<<<(FEAT * HID / 4 + 255) / 256, 256, 0, stream>>>(W_lin, Wlinb);
    build_wcomb_kernel<<<dim3(2048 / 64, HID / 64), 256, 0, stream>>>(dec_Wih, dec_Whh, W_lin, Wcomb);

    // all 216 recurrent steps in one persistent kernel
    lstm_persist<<<NGRP * NJT, 256, 0, stream>>>(Xbf, Wenc, enc_b, Wdec1, Wcomb, dec_b,
                                                 hbufA, hbufB, Hdec, flags);

    // batched output projection (48 x 256 rows @ W_lin^T)
    final_proj_kernel<<<(TOUT * BATCH) / 32, 128, 0, stream>>>(Hdec, Wlinb, out);
}